// Round 3
// baseline (8550.100 us; speedup 1.0000x reference)
//
#include <hip/hip_runtime.h>
#include <hip/hip_bf16.h>
#include <cmath>

#define NN 100000   // nodes
#define EE 600000   // edges
#define BB 512      // graphs
#define LL 10       // labels
// H=128; L1 256->512, L2 512->256, L3 256->128, L4 128->128, L5 128->10 (col-picked)

typedef __attribute__((ext_vector_type(8))) short  bf16x8;
typedef __attribute__((ext_vector_type(4))) float  f32x4;
typedef unsigned int uint;
typedef unsigned short ushort;

__device__ __forceinline__ float elu_f(float x){ return x > 0.f ? x : expm1f(x); }

__device__ __forceinline__ ushort bf16_rne(float f){
  uint u = __float_as_uint(f);
  return (ushort)((u + 0x7FFFu + ((u >> 16) & 1u)) >> 16);
}

__device__ __forceinline__ f32x4 MFMA(bf16x8 a, bf16x8 b, f32x4 c){
  return __builtin_amdgcn_mfma_f32_16x16x32_bf16(a, b, c, 0, 0, 0);
}

// Monotone float<->uint encoding for atomic max/min on floats
__device__ __forceinline__ unsigned enc_f(float f){
  unsigned u = __float_as_uint(f);
  return (u & 0x80000000u) ? ~u : (u | 0x80000000u);
}
__device__ __forceinline__ float dec_f(unsigned u){
  return (u & 0x80000000u) ? __uint_as_float(u ^ 0x80000000u) : __uint_as_float(~u);
}
#define ENC_NEG_INF 0x007FFFFFu

// ---------------------------------------------------------------------------
// kReps: repsF[n] = 512B row: [hi bf16 k=0..127][lo bf16 k=0..127].
// ---------------------------------------------------------------------------
__global__ __launch_bounds__(256) void kReps(const float* __restrict__ r0,
                                             const float* __restrict__ r1,
                                             ushort* __restrict__ repsF){
  int gid = blockIdx.x*256 + threadIdx.x;          // N*16 threads
  int n = gid >> 4, k8 = gid & 15;
  const float4* a = (const float4*)(r0 + (size_t)n*128 + k8*8);
  const float4* b = (const float4*)(r1 + (size_t)n*128 + k8*8);
  float4 x0 = a[0], x1 = a[1], y0 = b[0], y1 = b[1];
  float d[8] = {x0.x-y0.x, x0.y-y0.y, x0.z-y0.z, x0.w-y0.w,
                x1.x-y1.x, x1.y-y1.y, x1.z-y1.z, x1.w-y1.w};
  ushort hi[8], lo[8];
  #pragma unroll
  for (int j=0;j<8;++j){
    hi[j] = bf16_rne(d[j]);
    float fh = __uint_as_float(((uint)hi[j])<<16);
    lo[j] = bf16_rne(d[j] - fh);
  }
  ushort* dh = repsF + (size_t)n*256 + k8*8;
  ushort* dl = dh + 128;
  #pragma unroll
  for (int j=0;j<8;++j){ dh[j] = hi[j]; dl[j] = lo[j]; }
}

// ---------------------------------------------------------------------------
// kPrepW: weight [K][N] fp32 -> MFMA-fragment bf16 hi/lo:
//   dst[part][kt][nt][lane][j] with k = kt*32+(l>>4)*8+j, n = nt*16+(l&15).
// ---------------------------------------------------------------------------
__global__ __launch_bounds__(256) void kPrepW(const float* __restrict__ W, int N,
                                              int KT, int NT, ushort* __restrict__ dst){
  int gid = blockIdx.x*256 + threadIdx.x;
  int total = KT*NT*64;
  if (gid >= total) return;
  int l = gid & 63, tile = gid >> 6;
  int kt = tile / NT, nt = tile % NT;
  int kbase = kt*32 + (l>>4)*8;
  int n = nt*16 + (l&15);
  int partStride = KT*NT*512;
  int base = tile*512 + l*8;
  #pragma unroll
  for (int j=0;j<8;++j){
    float f = W[(size_t)(kbase+j)*N + n];
    ushort h = bf16_rne(f);
    float fh = __uint_as_float(((uint)h)<<16);
    dst[base + j] = h;
    dst[partStride + base + j] = bf16_rne(f - fh);
  }
}

// ---------------------------------------------------------------------------
// kMLP R3: fused MFMA layers 1..5, 64 edges/block, 4 waves.
// Layer-1 A-frags gathered straight from global repsF (no LDS staging, no
// staging barriers).  Single 2080-chunk LDS region (33.3 KB) recycled:
//   A2 = h1 128-col sub-chunk (hi at kg*65, lo at 1040+kg*65)
//   A3 = h2 128-col half      (same layout, layer-3 K split in two slices)
//   A4 = h3 (128 cols)        (same layout)
// -> 3 blocks/CU (VGPR-capped), 14 barriers/block vs 16 at 2 blocks in R2.
// Wave w: m-tiles mtw=(w&1)*2..+1, n-half nth=w>>1.
// ---------------------------------------------------------------------------
__global__ __launch_bounds__(256, 3) void kMLP(
    const ushort* __restrict__ repsF,
    const ushort* __restrict__ W1F, const ushort* __restrict__ W2F,
    const ushort* __restrict__ W3F, const ushort* __restrict__ W4F,
    const float* __restrict__ b1, const float* __restrict__ b2,
    const float* __restrict__ b3, const float* __restrict__ b4,
    const float* __restrict__ W5, const float* __restrict__ b5,
    const int* __restrict__ edge_index, const int* __restrict__ batch,
    const int* __restrict__ y,
    float* __restrict__ scores, int* __restrict__ ebatch)
{
  __shared__ __align__(16) short sAF[16640];   // 2080 chunks * 16 B = 33280 B
  __shared__ float sScore[64];
  __shared__ int sTy[64], sEb[64];

  const int tid = threadIdx.x;
  const int w = tid >> 6, l = tid & 63;
  const int quad = l >> 4, r16 = l & 15;
  const int mtw = (w & 1) * 2;       // wave's m-tiles: mtw, mtw+1
  const int nth = w >> 1;            // wave's n-half
  const int e0 = blockIdx.x * 64;

  if (tid < 64){
    int s = edge_index[e0 + tid];
    int eb = batch[s];
    sEb[tid] = eb; sTy[tid] = y[eb]; sScore[tid] = 0.f;
  }

  // per-lane node base pointers for layer-1 A-frag gathers
  const int eA = e0 + mtw*16 + r16;            // edge for mtl=0 (this lane's row)
  const int nS0 = edge_index[eA],       nS1 = edge_index[eA + 16];
  const int nD0 = edge_index[EE + eA],  nD1 = edge_index[EE + eA + 16];
  const ushort* aS0 = repsF + (size_t)nS0*256;
  const ushort* aS1 = repsF + (size_t)nS1*256;
  const ushort* aD0 = repsF + (size_t)nD0*256;
  const ushort* aD1 = repsF + (size_t)nD1*256;

  uint* ldsu = (uint*)sAF;

  // ---- layers 1+2 ----
  f32x4 C2[16];
  #pragma unroll
  for (int i=0;i<16;++i) C2[i] = (f32x4)0.f;

  for (int kc = 0; kc < 2; ++kc){              // 256-col chunk of h1
    f32x4 C1[16];
    #pragma unroll
    for (int i=0;i<16;++i) C1[i] = (f32x4)0.f;

    for (int half = 0; half < 2; ++half){      // K: src rows then dst rows
      const ushort* a0 = half ? aD0 : aS0;
      const ushort* a1 = half ? aD1 : aS1;
      for (int kt = 0; kt < 4; ++kt){
        const int ko = kt*32 + quad*8;
        bf16x8 Ah0 = *(const bf16x8*)(a0 + ko);
        bf16x8 Ah1 = *(const bf16x8*)(a1 + ko);
        bf16x8 Al0 = *(const bf16x8*)(a0 + 128 + ko);
        bf16x8 Al1 = *(const bf16x8*)(a1 + 128 + ko);
        int ktAbs = half*4 + kt;               // W1 k-tile (KT=8)
        const bf16x8* Wf = (const bf16x8*)W1F;
        #pragma unroll 2
        for (int ntl = 0; ntl < 8; ++ntl){
          int nt = kc*16 + nth*8 + ntl;        // 0..31 (NT=32)
          bf16x8 Bh = Wf[(ktAbs*32 + nt)*64 + l];
          bf16x8 Bl = Wf[(8*32*64) + (ktAbs*32 + nt)*64 + l];
          f32x4 c0 = C1[ntl*2+0], c1 = C1[ntl*2+1];
          c0 = MFMA(Ah0, Bh, c0); c1 = MFMA(Ah1, Bh, c1);
          c0 = MFMA(Ah0, Bl, c0); c1 = MFMA(Ah1, Bl, c1);
          c0 = MFMA(Al0, Bh, c0); c1 = MFMA(Al1, Bh, c1);
          C1[ntl*2+0] = c0; C1[ntl*2+1] = c1;
        }
      }
    }

    // sub-chunk epilogue (128 cols) -> A2, then layer-2 partial
    for (int sc = 0; sc < 2; ++sc){
      __syncthreads();                         // prior A2 readers done
      if (nth == sc){                          // owner waves write their frags
        #pragma unroll
        for (int ntl = 0; ntl < 8; ++ntl){
          #pragma unroll
          for (int mtl = 0; mtl < 2; ++mtl){
            f32x4 v = C1[ntl*2+mtl];
            int n = (kc*16 + sc*8 + ntl)*16 + r16;   // abs col of h1
            float bv = b1[n];
            ushort hi[4], lo[4];
            #pragma unroll
            for (int r=0;r<4;++r){
              float f = elu_f(v[r] + bv);
              hi[r] = bf16_rne(f);
              float fh = __uint_as_float(((uint)hi[r])<<16);
              lo[r] = bf16_rne(f - fh);
            }
            int k2 = ntl*16 + r16;                    // col within sub-chunk
            int kg = k2 >> 3, j = k2 & 7;
            int m0 = (mtw+mtl)*16 + quad*4;
            uint v01h = (uint)hi[0] | ((uint)hi[1]<<16);
            uint v23h = (uint)hi[2] | ((uint)hi[3]<<16);
            uint v01l = (uint)lo[0] | ((uint)lo[1]<<16);
            uint v23l = (uint)lo[2] | ((uint)lo[3]<<16);
            uint t01h = __shfl_xor(v01h, 1), t23h = __shfl_xor(v23h, 1);
            uint t01l = __shfl_xor(v01l, 1), t23l = __shfl_xor(v23l, 1);
            int jj = (j & ~1) >> 1;
            int cbH = kg*65;                          // A2 hi
            int cbL = 1040 + kg*65;                   // A2 lo
            if (!(l & 1)){
              ldsu[(cbH + m0 + 0)*4 + jj] = (v01h & 0xFFFFu) | (t01h << 16);
              ldsu[(cbH + m0 + 1)*4 + jj] = (v01h >> 16) | (t01h & 0xFFFF0000u);
              ldsu[(cbL + m0 + 0)*4 + jj] = (v01l & 0xFFFFu) | (t01l << 16);
              ldsu[(cbL + m0 + 1)*4 + jj] = (v01l >> 16) | (t01l & 0xFFFF0000u);
            } else {
              ldsu[(cbH + m0 + 2)*4 + jj] = (t23h & 0xFFFFu) | (v23h << 16);
              ldsu[(cbH + m0 + 3)*4 + jj] = (t23h >> 16) | (v23h & 0xFFFF0000u);
              ldsu[(cbL + m0 + 2)*4 + jj] = (t23l & 0xFFFFu) | (v23l << 16);
              ldsu[(cbL + m0 + 3)*4 + jj] = (t23l >> 16) | (v23l & 0xFFFF0000u);
            }
          }
        }
      }
      __syncthreads();

      // layer-2 partial: K-slice = this sub-chunk (128)
      for (int kt2 = 0; kt2 < 4; ++kt2){
        bf16x8 Ah[2], Al[2];
        #pragma unroll
        for (int mtl=0;mtl<2;++mtl){
          int m = (mtw+mtl)*16 + r16;
          Ah[mtl] = *(const bf16x8*)(sAF + ((kt2*4+quad)*65 + m)*8);
          Al[mtl] = *(const bf16x8*)(sAF + (1040 + (kt2*4+quad)*65 + m)*8);
        }
        int ktAbs = kc*8 + sc*4 + kt2;         // W2 k-tile (KT=16)
        const bf16x8* Wf = (const bf16x8*)W2F;
        #pragma unroll 2
        for (int ntl = 0; ntl < 8; ++ntl){
          int nt = nth*8 + ntl;                // 0..15 (NT=16)
          bf16x8 Bh = Wf[(ktAbs*16 + nt)*64 + l];
          bf16x8 Bl = Wf[(16*16*64) + (ktAbs*16 + nt)*64 + l];
          f32x4 c0 = C2[ntl*2+0], c1 = C2[ntl*2+1];
          c0 = MFMA(Ah[0], Bh, c0); c1 = MFMA(Ah[1], Bh, c1);
          c0 = MFMA(Ah[0], Bl, c0); c1 = MFMA(Ah[1], Bl, c1);
          c0 = MFMA(Al[0], Bh, c0); c1 = MFMA(Al[1], Bh, c1);
          C2[ntl*2+0] = c0; C2[ntl*2+1] = c1;
        }
      }
    }
  }

  // ---- layer 3 in two 128-col K-slices (A3 = wave-half of h2) ----
  f32x4 C3[8];
  #pragma unroll
  for (int i=0;i<8;++i) C3[i] = (f32x4)0.f;
  for (int sc2 = 0; sc2 < 2; ++sc2){
    __syncthreads();                           // prior region readers done
    if (nth == sc2){                           // owner waves write h2 cols sc2*128..
      #pragma unroll
      for (int ntl = 0; ntl < 8; ++ntl){
        #pragma unroll
        for (int mtl = 0; mtl < 2; ++mtl){
          f32x4 v = C2[ntl*2+mtl];
          int n2 = (nth*8 + ntl)*16 + r16;     // abs col of h2
          float bv = b2[n2];
          ushort hi[4], lo[4];
          #pragma unroll
          for (int r=0;r<4;++r){
            float f = elu_f(v[r] + bv);
            hi[r] = bf16_rne(f);
            float fh = __uint_as_float(((uint)hi[r])<<16);
            lo[r] = bf16_rne(f - fh);
          }
          int k2 = ntl*16 + r16;               // col within 128-slice
          int kg = k2 >> 3, j = k2 & 7, jj = (j & ~1) >> 1;
          int m0 = (mtw+mtl)*16 + quad*4;
          uint v01h = (uint)hi[0] | ((uint)hi[1]<<16);
          uint v23h = (uint)hi[2] | ((uint)hi[3]<<16);
          uint v01l = (uint)lo[0] | ((uint)lo[1]<<16);
          uint v23l = (uint)lo[2] | ((uint)lo[3]<<16);
          uint t01h = __shfl_xor(v01h, 1), t23h = __shfl_xor(v23h, 1);
          uint t01l = __shfl_xor(v01l, 1), t23l = __shfl_xor(v23l, 1);
          int cbH = kg*65, cbL = 1040 + kg*65;
          if (!(l & 1)){
            ldsu[(cbH + m0 + 0)*4 + jj] = (v01h & 0xFFFFu) | (t01h << 16);
            ldsu[(cbH + m0 + 1)*4 + jj] = (v01h >> 16) | (t01h & 0xFFFF0000u);
            ldsu[(cbL + m0 + 0)*4 + jj] = (v01l & 0xFFFFu) | (t01l << 16);
            ldsu[(cbL + m0 + 1)*4 + jj] = (v01l >> 16) | (t01l & 0xFFFF0000u);
          } else {
            ldsu[(cbH + m0 + 2)*4 + jj] = (t23h & 0xFFFFu) | (v23h << 16);
            ldsu[(cbH + m0 + 3)*4 + jj] = (t23h >> 16) | (v23h & 0xFFFF0000u);
            ldsu[(cbL + m0 + 2)*4 + jj] = (t23l & 0xFFFFu) | (v23l << 16);
            ldsu[(cbL + m0 + 3)*4 + jj] = (t23l >> 16) | (v23l & 0xFFFF0000u);
          }
        }
      }
    }
    __syncthreads();

    for (int kt = 0; kt < 4; ++kt){
      bf16x8 Ah[2], Al[2];
      #pragma unroll
      for (int mtl=0;mtl<2;++mtl){
        int m = (mtw+mtl)*16 + r16;
        Ah[mtl] = *(const bf16x8*)(sAF + ((kt*4+quad)*65 + m)*8);
        Al[mtl] = *(const bf16x8*)(sAF + (1040 + (kt*4+quad)*65 + m)*8);
      }
      int ktAbs = sc2*4 + kt;                  // W3 k-tile (KT=8)
      const bf16x8* Wf = (const bf16x8*)W3F;
      #pragma unroll 2
      for (int ntl = 0; ntl < 4; ++ntl){
        int nt = nth*4 + ntl;                  // 0..7 (NT=8)
        bf16x8 Bh = Wf[(ktAbs*8 + nt)*64 + l];
        bf16x8 Bl = Wf[(8*8*64) + (ktAbs*8 + nt)*64 + l];
        f32x4 c0 = C3[ntl*2+0], c1 = C3[ntl*2+1];
        c0 = MFMA(Ah[0], Bh, c0); c1 = MFMA(Ah[1], Bh, c1);
        c0 = MFMA(Ah[0], Bl, c0); c1 = MFMA(Ah[1], Bl, c1);
        c0 = MFMA(Al[0], Bh, c0); c1 = MFMA(Al[1], Bh, c1);
        C3[ntl*2+0] = c0; C3[ntl*2+1] = c1;
      }
    }
  }

  // ---- C3 epilogue: h3 = C3 + b3 (NO elu) -> A4 ----
  __syncthreads();                             // all L3 reads done
  #pragma unroll
  for (int ntl = 0; ntl < 4; ++ntl){
    #pragma unroll
    for (int mtl = 0; mtl < 2; ++mtl){
      f32x4 v = C3[ntl*2+mtl];
      int n3 = (nth*4 + ntl)*16 + r16;         // 0..127
      float bv = b3[n3];
      ushort hi[4], lo[4];
      #pragma unroll
      for (int r=0;r<4;++r){
        float f = v[r] + bv;
        hi[r] = bf16_rne(f);
        float fh = __uint_as_float(((uint)hi[r])<<16);
        lo[r] = bf16_rne(f - fh);
      }
      int kg = n3 >> 3, j = n3 & 7, jj = (j & ~1) >> 1;
      int m0 = (mtw+mtl)*16 + quad*4;
      uint v01h = (uint)hi[0] | ((uint)hi[1]<<16);
      uint v23h = (uint)hi[2] | ((uint)hi[3]<<16);
      uint v01l = (uint)lo[0] | ((uint)lo[1]<<16);
      uint v23l = (uint)lo[2] | ((uint)lo[3]<<16);
      uint t01h = __shfl_xor(v01h, 1), t23h = __shfl_xor(v23h, 1);
      uint t01l = __shfl_xor(v01l, 1), t23l = __shfl_xor(v23l, 1);
      int cbH = kg*65, cbL = 1040 + kg*65;     // A4 region
      if (!(l & 1)){
        ldsu[(cbH + m0 + 0)*4 + jj] = (v01h & 0xFFFFu) | (t01h << 16);
        ldsu[(cbH + m0 + 1)*4 + jj] = (v01h >> 16) | (t01h & 0xFFFF0000u);
        ldsu[(cbL + m0 + 0)*4 + jj] = (v01l & 0xFFFFu) | (t01l << 16);
        ldsu[(cbL + m0 + 1)*4 + jj] = (v01l >> 16) | (t01l & 0xFFFF0000u);
      } else {
        ldsu[(cbH + m0 + 2)*4 + jj] = (t23h & 0xFFFFu) | (v23h << 16);
        ldsu[(cbH + m0 + 3)*4 + jj] = (t23h >> 16) | (v23h & 0xFFFF0000u);
        ldsu[(cbL + m0 + 2)*4 + jj] = (t23l & 0xFFFFu) | (v23l << 16);
        ldsu[(cbL + m0 + 3)*4 + jj] = (t23l >> 16) | (v23l & 0xFFFF0000u);
      }
    }
  }
  __syncthreads();

  // ---- layer 4: C4 = A4 @ W4 (K=128) ----
  f32x4 C4[8];
  #pragma unroll
  for (int i=0;i<8;++i) C4[i] = (f32x4)0.f;
  for (int kt = 0; kt < 4; ++kt){
    bf16x8 Ah[2], Al[2];
    #pragma unroll
    for (int mtl=0;mtl<2;++mtl){
      int m = (mtw+mtl)*16 + r16;
      Ah[mtl] = *(const bf16x8*)(sAF + ((kt*4+quad)*65 + m)*8);
      Al[mtl] = *(const bf16x8*)(sAF + (1040 + (kt*4+quad)*65 + m)*8);
    }
    const bf16x8* Wf = (const bf16x8*)W4F;
    #pragma unroll 2
    for (int ntl = 0; ntl < 4; ++ntl){
      int nt = nth*4 + ntl;                    // 0..7 (NT=8)
      bf16x8 Bh = Wf[(kt*8 + nt)*64 + l];
      bf16x8 Bl = Wf[(4*8*64) + (kt*8 + nt)*64 + l];
      f32x4 c0 = C4[ntl*2+0], c1 = C4[ntl*2+1];
      c0 = MFMA(Ah[0], Bh, c0); c1 = MFMA(Ah[1], Bh, c1);
      c0 = MFMA(Ah[0], Bl, c0); c1 = MFMA(Ah[1], Bl, c1);
      c0 = MFMA(Al[0], Bh, c0); c1 = MFMA(Al[1], Bh, c1);
      C4[ntl*2+0] = c0; C4[ntl*2+1] = c1;
    }
  }

  // ---- layer 5: score = elu(C4+b4) . W5[:,t] ----
  float p[2][4] = {{0.f,0.f,0.f,0.f},{0.f,0.f,0.f,0.f}};
  #pragma unroll
  for (int ntl = 0; ntl < 4; ++ntl){
    int n4 = (nth*4 + ntl)*16 + r16;
    float bv = b4[n4];
    const float* w5r = W5 + n4*LL;
    #pragma unroll
    for (int mtl = 0; mtl < 2; ++mtl){
      f32x4 c = C4[ntl*2+mtl];
      #pragma unroll
      for (int r=0;r<4;++r){
        int m = (mtw+mtl)*16 + quad*4 + r;
        p[mtl][r] += elu_f(c[r] + bv) * w5r[sTy[m]];
      }
    }
  }
  #pragma unroll
  for (int d = 8; d >= 1; d >>= 1){
    #pragma unroll
    for (int mtl=0;mtl<2;++mtl)
      #pragma unroll
      for (int r=0;r<4;++r)
        p[mtl][r] += __shfl_down(p[mtl][r], d, 16);
  }
  if (r16 == 0){
    #pragma unroll
    for (int mtl=0;mtl<2;++mtl)
      #pragma unroll
      for (int r=0;r<4;++r)
        atomicAdd(&sScore[(mtw+mtl)*16 + quad*4 + r], p[mtl][r]);
  }
  __syncthreads();
  if (tid < 64){
    scores[e0 + tid] = sScore[tid] + b5[sTy[tid]];
    ebatch[e0 + tid] = sEb[tid];
  }
}

// ---------------------------------------------------------------------------
// Segment softmax / argmax passes (unchanged, verified)
// ---------------------------------------------------------------------------
__global__ void kInitSeg(unsigned* segmax, float* segsum, unsigned* gmax, int* gact){
  int b = blockIdx.x*blockDim.x + threadIdx.x;
  if (b < BB){ segmax[b] = ENC_NEG_INF; segsum[b] = 0.f; gmax[b] = ENC_NEG_INF; gact[b] = 0x7FFFFFFF; }
}

__global__ __launch_bounds__(256) void kSegMax(const float* __restrict__ scores,
                                               const int* __restrict__ eb,
                                               unsigned* __restrict__ segmax){
  __shared__ unsigned l[BB];
  for (int b = threadIdx.x; b < BB; b += 256) l[b] = 0u;
  __syncthreads();
  for (int e = blockIdx.x*256 + threadIdx.x; e < EE; e += gridDim.x*256)
    atomicMax(&l[eb[e]], enc_f(scores[e]));
  __syncthreads();
  for (int b = threadIdx.x; b < BB; b += 256)
    if (l[b]) atomicMax(&segmax[b], l[b]);
}

__global__ __launch_bounds__(256) void kExpSum(const float* __restrict__ scores,
                                               const int* __restrict__ eb,
                                               const unsigned* __restrict__ segmax,
                                               float* __restrict__ segsum,
                                               float* __restrict__ outprobs){
  __shared__ float l[BB];
  for (int b = threadIdx.x; b < BB; b += 256) l[b] = 0.f;
  __syncthreads();
  for (int e = blockIdx.x*256 + threadIdx.x; e < EE; e += gridDim.x*256){
    int b = eb[e];
    float ex = expf(scores[e] - dec_f(segmax[b]));
    outprobs[e] = ex;
    atomicAdd(&l[b], ex);
  }
  __syncthreads();
  for (int b = threadIdx.x; b < BB; b += 256)
    if (l[b] != 0.f) atomicAdd(&segsum[b], l[b]);
}

__global__ __launch_bounds__(256) void kProbMax(float* __restrict__ outprobs,
                                                const int* __restrict__ eb,
                                                const float* __restrict__ segsum,
                                                unsigned* __restrict__ gmax){
  __shared__ unsigned l[BB];
  for (int b = threadIdx.x; b < BB; b += 256) l[b] = 0u;
  __syncthreads();
  for (int e = blockIdx.x*256 + threadIdx.x; e < EE; e += gridDim.x*256){
    int b = eb[e];
    float p = outprobs[e] / segsum[b];
    outprobs[e] = p;
    atomicMax(&l[b], enc_f(p));
  }
  __syncthreads();
  for (int b = threadIdx.x; b < BB; b += 256)
    if (l[b]) atomicMax(&gmax[b], l[b]);
}

__global__ __launch_bounds__(256) void kArgMin(const float* __restrict__ outprobs,
                                               const int* __restrict__ eb,
                                               const unsigned* __restrict__ gmax,
                                               int* __restrict__ gact){
  __shared__ int l[BB];
  for (int b = threadIdx.x; b < BB; b += 256) l[b] = 0x7FFFFFFF;
  __syncthreads();
  for (int e = blockIdx.x*256 + threadIdx.x; e < EE; e += gridDim.x*256){
    int b = eb[e];
    if (enc_f(outprobs[e]) == gmax[b]) atomicMin(&l[b], e);
  }
  __syncthreads();
  for (int b = threadIdx.x; b < BB; b += 256)
    if (l[b] != 0x7FFFFFFF) atomicMin(&gact[b], l[b]);
}

__global__ void kFinal(const unsigned* __restrict__ gmax, const int* __restrict__ gact,
                       float* __restrict__ out){
  int b = threadIdx.x;
  if (b < BB){
    out[EE + b]      = dec_f(gmax[b]);
    out[EE + BB + b] = (float)gact[b];
  }
}

// ---------------------------------------------------------------------------
extern "C" void kernel_launch(void* const* d_in, const int* in_sizes, int n_in,
                              void* d_out, int out_size, void* d_ws, size_t ws_size,
                              hipStream_t stream){
  const float* r0 = (const float*)d_in[0];
  const float* r1 = (const float*)d_in[1];
  const float* W1 = (const float*)d_in[2];
  const float* b1 = (const float*)d_in[3];
  const float* W2 = (const float*)d_in[4];
  const float* b2 = (const float*)d_in[5];
  const float* W3 = (const float*)d_in[6];
  const float* b3 = (const float*)d_in[7];
  const float* W4 = (const float*)d_in[8];
  const float* b4 = (const float*)d_in[9];
  const float* W5 = (const float*)d_in[10];
  const float* b5 = (const float*)d_in[11];
  const int* edge_index = (const int*)d_in[12];
  const int* batch = (const int*)d_in[13];
  const int* y = (const int*)d_in[14];
  float* out = (float*)d_out;

  char* ws = (char*)d_ws;
  size_t off = 0;
  float*    scores = (float*)(ws + off);    off += (size_t)EE*4;
  int*      ebatch = (int*)(ws + off);      off += (size_t)EE*4;
  unsigned* segmax = (unsigned*)(ws + off); off += BB*4;
  float*    segsum = (float*)(ws + off);    off += BB*4;
  unsigned* gmax   = (unsigned*)(ws + off); off += BB*4;
  int*      gact   = (int*)(ws + off);      off += BB*4;
  off = (off + 511) & ~(size_t)511;
  ushort* repsF = (ushort*)(ws + off);      off += (size_t)NN*256*2;   // 51.2 MB
  ushort* W1F   = (ushort*)(ws + off);      off += (size_t)2*8*32*512*2;
  ushort* W2F   = (ushort*)(ws + off);      off += (size_t)2*16*16*512*2;
  ushort* W3F   = (ushort*)(ws + off);      off += (size_t)2*8*8*512*2;
  ushort* W4F   = (ushort*)(ws + off);      off += (size_t)2*4*8*512*2;

  kInitSeg<<<2, 256, 0, stream>>>(segmax, segsum, gmax, gact);
  kReps<<<(NN*16)/256, 256, 0, stream>>>(r0, r1, repsF);
  kPrepW<<<(8*32*64)/256, 256, 0, stream>>>(W1, 512, 8, 32, W1F);
  kPrepW<<<(16*16*64)/256, 256, 0, stream>>>(W2, 256, 16, 16, W2F);
  kPrepW<<<(8*8*64)/256, 256, 0, stream>>>(W3, 128, 8, 8, W3F);
  kPrepW<<<(4*8*64)/256, 256, 0, stream>>>(W4, 128, 4, 8, W4F);

  kMLP<<<EE/64, 256, 0, stream>>>(repsF, W1F, W2F, W3F, W4F,
                                  b1, b2, b3, b4, W5, b5,
                                  edge_index, batch, y, scores, ebatch);

  kSegMax <<<256, 256, 0, stream>>>(scores, ebatch, segmax);
  kExpSum <<<256, 256, 0, stream>>>(scores, ebatch, segmax, segsum, out);
  kProbMax<<<256, 256, 0, stream>>>(out, ebatch, segsum, gmax);
  kArgMin <<<256, 256, 0, stream>>>(out, ebatch, gmax, gact);
  kFinal  <<<1, 512, 0, stream>>>(gmax, gact, out);
}

// Round 4
// 4075.657 us; speedup vs baseline: 2.0978x; 2.0978x over previous
//
#include <hip/hip_runtime.h>
#include <hip/hip_bf16.h>
#include <cmath>

#define NN 100000   // nodes
#define EE 600000   // edges
#define BB 512      // graphs
#define LL 10       // labels
// H=128; L1 256->512, L2 512->256, L3 256->128, L4 128->128, L5 128->10 (col-picked)

typedef __attribute__((ext_vector_type(8))) short  bf16x8;
typedef __attribute__((ext_vector_type(4))) float  f32x4;
typedef unsigned int uint;
typedef unsigned short ushort;

__device__ __forceinline__ float elu_f(float x){ return x > 0.f ? x : expm1f(x); }

__device__ __forceinline__ ushort bf16_rne(float f){
  uint u = __float_as_uint(f);
  return (ushort)((u + 0x7FFFu + ((u >> 16) & 1u)) >> 16);
}

__device__ __forceinline__ f32x4 MFMA(bf16x8 a, bf16x8 b, f32x4 c){
  return __builtin_amdgcn_mfma_f32_16x16x32_bf16(a, b, c, 0, 0, 0);
}

// Monotone float<->uint encoding for atomic max/min on floats
__device__ __forceinline__ unsigned enc_f(float f){
  unsigned u = __float_as_uint(f);
  return (u & 0x80000000u) ? ~u : (u | 0x80000000u);
}
__device__ __forceinline__ float dec_f(unsigned u){
  return (u & 0x80000000u) ? __uint_as_float(u ^ 0x80000000u) : __uint_as_float(~u);
}
#define ENC_NEG_INF 0x007FFFFFu

// ---------------------------------------------------------------------------
// kReps: repsF[n] = 512B row: [hi bf16 k=0..127][lo bf16 k=0..127].
// ---------------------------------------------------------------------------
__global__ __launch_bounds__(256) void kReps(const float* __restrict__ r0,
                                             const float* __restrict__ r1,
                                             ushort* __restrict__ repsF){
  int gid = blockIdx.x*256 + threadIdx.x;          // N*16 threads
  int n = gid >> 4, k8 = gid & 15;
  const float4* a = (const float4*)(r0 + (size_t)n*128 + k8*8);
  const float4* b = (const float4*)(r1 + (size_t)n*128 + k8*8);
  float4 x0 = a[0], x1 = a[1], y0 = b[0], y1 = b[1];
  float d[8] = {x0.x-y0.x, x0.y-y0.y, x0.z-y0.z, x0.w-y0.w,
                x1.x-y1.x, x1.y-y1.y, x1.z-y1.z, x1.w-y1.w};
  ushort hi[8], lo[8];
  #pragma unroll
  for (int j=0;j<8;++j){
    hi[j] = bf16_rne(d[j]);
    float fh = __uint_as_float(((uint)hi[j])<<16);
    lo[j] = bf16_rne(d[j] - fh);
  }
  ushort* dh = repsF + (size_t)n*256 + k8*8;
  ushort* dl = dh + 128;
  #pragma unroll
  for (int j=0;j<8;++j){ dh[j] = hi[j]; dl[j] = lo[j]; }
}

// ---------------------------------------------------------------------------
// kPrepW: weight [K][N] fp32 -> MFMA-fragment bf16 hi/lo:
//   dst[part][kt][nt][lane][j] with k = kt*32+(l>>4)*8+j, n = nt*16+(l&15).
// ---------------------------------------------------------------------------
__global__ __launch_bounds__(256) void kPrepW(const float* __restrict__ W, int N,
                                              int KT, int NT, ushort* __restrict__ dst){
  int gid = blockIdx.x*256 + threadIdx.x;
  int total = KT*NT*64;
  if (gid >= total) return;
  int l = gid & 63, tile = gid >> 6;
  int kt = tile / NT, nt = tile % NT;
  int kbase = kt*32 + (l>>4)*8;
  int n = nt*16 + (l&15);
  int partStride = KT*NT*512;
  int base = tile*512 + l*8;
  #pragma unroll
  for (int j=0;j<8;++j){
    float f = W[(size_t)(kbase+j)*N + n];
    ushort h = bf16_rne(f);
    float fh = __uint_as_float(((uint)h)<<16);
    dst[base + j] = h;
    dst[partStride + base + j] = bf16_rne(f - fh);
  }
}

// ---------------------------------------------------------------------------
// kMLP R4: R3 structure (global A-gather, 33 KB LDS, 14 barriers) with the
// register budget restored: launch_bounds(256,2) -> 256-VGPR cap, no spills
// (R3's (256,3) cap at ~170 VGPR spilled C1/C2 -> 23 GB scratch writes).
// Headroom spent on latency hiding: full ntl unrolls (16 B-loads in flight)
// + manual A-frag prefetch across the flattened (half,kt) loop.
// Wave w: m-tiles mtw=(w&1)*2..+1, n-half nth=w>>1.
// ---------------------------------------------------------------------------
__global__ __launch_bounds__(256, 2) void kMLP(
    const ushort* __restrict__ repsF,
    const ushort* __restrict__ W1F, const ushort* __restrict__ W2F,
    const ushort* __restrict__ W3F, const ushort* __restrict__ W4F,
    const float* __restrict__ b1, const float* __restrict__ b2,
    const float* __restrict__ b3, const float* __restrict__ b4,
    const float* __restrict__ W5, const float* __restrict__ b5,
    const int* __restrict__ edge_index, const int* __restrict__ batch,
    const int* __restrict__ y,
    float* __restrict__ scores, int* __restrict__ ebatch)
{
  __shared__ __align__(16) short sAF[16640];   // 2080 chunks * 16 B = 33280 B
  __shared__ float sScore[64];
  __shared__ int sTy[64], sEb[64];

  const int tid = threadIdx.x;
  const int w = tid >> 6, l = tid & 63;
  const int quad = l >> 4, r16 = l & 15;
  const int mtw = (w & 1) * 2;       // wave's m-tiles: mtw, mtw+1
  const int nth = w >> 1;            // wave's n-half
  const int e0 = blockIdx.x * 64;

  if (tid < 64){
    int s = edge_index[e0 + tid];
    int eb = batch[s];
    sEb[tid] = eb; sTy[tid] = y[eb]; sScore[tid] = 0.f;
  }

  // per-lane node base pointers for layer-1 A-frag gathers
  const int eA = e0 + mtw*16 + r16;            // edge of this lane's MFMA row
  const int nS0 = edge_index[eA],       nS1 = edge_index[eA + 16];
  const int nD0 = edge_index[EE + eA],  nD1 = edge_index[EE + eA + 16];
  const ushort* aS0 = repsF + (size_t)nS0*256;
  const ushort* aS1 = repsF + (size_t)nS1*256;
  const ushort* aD0 = repsF + (size_t)nD0*256;
  const ushort* aD1 = repsF + (size_t)nD1*256;

  uint* ldsu = (uint*)sAF;

  // ---- layers 1+2 ----
  f32x4 C2[16];
  #pragma unroll
  for (int i=0;i<16;++i) C2[i] = (f32x4)0.f;

  for (int kc = 0; kc < 2; ++kc){              // 256-col chunk of h1
    f32x4 C1[16];
    #pragma unroll
    for (int i=0;i<16;++i) C1[i] = (f32x4)0.f;

    // flattened (half,kt) = hk 0..7; ktAbs == hk.  A prefetched one hk ahead.
    bf16x8 nAh0, nAh1, nAl0, nAl1;
    {
      const int ko = quad*8;
      nAh0 = *(const bf16x8*)(aS0 + ko);
      nAh1 = *(const bf16x8*)(aS1 + ko);
      nAl0 = *(const bf16x8*)(aS0 + 128 + ko);
      nAl1 = *(const bf16x8*)(aS1 + 128 + ko);
    }
    for (int hk = 0; hk < 8; ++hk){
      bf16x8 Ah0 = nAh0, Ah1 = nAh1, Al0 = nAl0, Al1 = nAl1;
      if (hk < 7){
        int nhk = hk + 1;
        const ushort* a0 = (nhk < 4) ? aS0 : aD0;
        const ushort* a1 = (nhk < 4) ? aS1 : aD1;
        const int ko = (nhk & 3)*32 + quad*8;
        nAh0 = *(const bf16x8*)(a0 + ko);
        nAh1 = *(const bf16x8*)(a1 + ko);
        nAl0 = *(const bf16x8*)(a0 + 128 + ko);
        nAl1 = *(const bf16x8*)(a1 + 128 + ko);
      }
      const bf16x8* WfH = (const bf16x8*)W1F + (size_t)(hk*32 + kc*16 + nth*8)*64 + l;
      const bf16x8* WfL = WfH + 8*32*64;
      #pragma unroll
      for (int ntl = 0; ntl < 8; ++ntl){
        bf16x8 Bh = WfH[ntl*64];
        bf16x8 Bl = WfL[ntl*64];
        f32x4 c0 = C1[ntl*2+0], c1 = C1[ntl*2+1];
        c0 = MFMA(Ah0, Bh, c0); c1 = MFMA(Ah1, Bh, c1);
        c0 = MFMA(Ah0, Bl, c0); c1 = MFMA(Ah1, Bl, c1);
        c0 = MFMA(Al0, Bh, c0); c1 = MFMA(Al1, Bh, c1);
        C1[ntl*2+0] = c0; C1[ntl*2+1] = c1;
      }
    }

    // sub-chunk epilogue (128 cols) -> A2, then layer-2 partial
    for (int sc = 0; sc < 2; ++sc){
      __syncthreads();                         // prior A2 readers done
      if (nth == sc){                          // owner waves write their frags
        #pragma unroll
        for (int ntl = 0; ntl < 8; ++ntl){
          #pragma unroll
          for (int mtl = 0; mtl < 2; ++mtl){
            f32x4 v = C1[ntl*2+mtl];
            int n = (kc*16 + sc*8 + ntl)*16 + r16;   // abs col of h1
            float bv = b1[n];
            ushort hi[4], lo[4];
            #pragma unroll
            for (int r=0;r<4;++r){
              float f = elu_f(v[r] + bv);
              hi[r] = bf16_rne(f);
              float fh = __uint_as_float(((uint)hi[r])<<16);
              lo[r] = bf16_rne(f - fh);
            }
            int k2 = ntl*16 + r16;                    // col within sub-chunk
            int kg = k2 >> 3, j = k2 & 7;
            int m0 = (mtw+mtl)*16 + quad*4;
            uint v01h = (uint)hi[0] | ((uint)hi[1]<<16);
            uint v23h = (uint)hi[2] | ((uint)hi[3]<<16);
            uint v01l = (uint)lo[0] | ((uint)lo[1]<<16);
            uint v23l = (uint)lo[2] | ((uint)lo[3]<<16);
            uint t01h = __shfl_xor(v01h, 1), t23h = __shfl_xor(v23h, 1);
            uint t01l = __shfl_xor(v01l, 1), t23l = __shfl_xor(v23l, 1);
            int jj = (j & ~1) >> 1;
            int cbH = kg*65;                          // A2 hi
            int cbL = 1040 + kg*65;                   // A2 lo
            if (!(l & 1)){
              ldsu[(cbH + m0 + 0)*4 + jj] = (v01h & 0xFFFFu) | (t01h << 16);
              ldsu[(cbH + m0 + 1)*4 + jj] = (v01h >> 16) | (t01h & 0xFFFF0000u);
              ldsu[(cbL + m0 + 0)*4 + jj] = (v01l & 0xFFFFu) | (t01l << 16);
              ldsu[(cbL + m0 + 1)*4 + jj] = (v01l >> 16) | (t01l & 0xFFFF0000u);
            } else {
              ldsu[(cbH + m0 + 2)*4 + jj] = (t23h & 0xFFFFu) | (v23h << 16);
              ldsu[(cbH + m0 + 3)*4 + jj] = (t23h >> 16) | (v23h & 0xFFFF0000u);
              ldsu[(cbL + m0 + 2)*4 + jj] = (t23l & 0xFFFFu) | (v23l << 16);
              ldsu[(cbL + m0 + 3)*4 + jj] = (t23l >> 16) | (v23l & 0xFFFF0000u);
            }
          }
        }
      }
      __syncthreads();

      // layer-2 partial: K-slice = this sub-chunk (128)
      for (int kt2 = 0; kt2 < 4; ++kt2){
        bf16x8 Ah[2], Al[2];
        #pragma unroll
        for (int mtl=0;mtl<2;++mtl){
          int m = (mtw+mtl)*16 + r16;
          Ah[mtl] = *(const bf16x8*)(sAF + ((kt2*4+quad)*65 + m)*8);
          Al[mtl] = *(const bf16x8*)(sAF + (1040 + (kt2*4+quad)*65 + m)*8);
        }
        int ktAbs = kc*8 + sc*4 + kt2;         // W2 k-tile (KT=16)
        const bf16x8* WfH = (const bf16x8*)W2F + (size_t)(ktAbs*16 + nth*8)*64 + l;
        const bf16x8* WfL = WfH + 16*16*64;
        #pragma unroll
        for (int ntl = 0; ntl < 8; ++ntl){
          bf16x8 Bh = WfH[ntl*64];
          bf16x8 Bl = WfL[ntl*64];
          f32x4 c0 = C2[ntl*2+0], c1 = C2[ntl*2+1];
          c0 = MFMA(Ah[0], Bh, c0); c1 = MFMA(Ah[1], Bh, c1);
          c0 = MFMA(Ah[0], Bl, c0); c1 = MFMA(Ah[1], Bl, c1);
          c0 = MFMA(Al[0], Bh, c0); c1 = MFMA(Al[1], Bh, c1);
          C2[ntl*2+0] = c0; C2[ntl*2+1] = c1;
        }
      }
    }
  }

  // ---- layer 3 in two 128-col K-slices (A3 = wave-half of h2) ----
  f32x4 C3[8];
  #pragma unroll
  for (int i=0;i<8;++i) C3[i] = (f32x4)0.f;
  for (int sc2 = 0; sc2 < 2; ++sc2){
    __syncthreads();                           // prior region readers done
    if (nth == sc2){                           // owner waves write h2 cols sc2*128..
      #pragma unroll
      for (int ntl = 0; ntl < 8; ++ntl){
        #pragma unroll
        for (int mtl = 0; mtl < 2; ++mtl){
          f32x4 v = C2[ntl*2+mtl];
          int n2 = (nth*8 + ntl)*16 + r16;     // abs col of h2
          float bv = b2[n2];
          ushort hi[4], lo[4];
          #pragma unroll
          for (int r=0;r<4;++r){
            float f = elu_f(v[r] + bv);
            hi[r] = bf16_rne(f);
            float fh = __uint_as_float(((uint)hi[r])<<16);
            lo[r] = bf16_rne(f - fh);
          }
          int k2 = ntl*16 + r16;               // col within 128-slice
          int kg = k2 >> 3, j = k2 & 7, jj = (j & ~1) >> 1;
          int m0 = (mtw+mtl)*16 + quad*4;
          uint v01h = (uint)hi[0] | ((uint)hi[1]<<16);
          uint v23h = (uint)hi[2] | ((uint)hi[3]<<16);
          uint v01l = (uint)lo[0] | ((uint)lo[1]<<16);
          uint v23l = (uint)lo[2] | ((uint)lo[3]<<16);
          uint t01h = __shfl_xor(v01h, 1), t23h = __shfl_xor(v23h, 1);
          uint t01l = __shfl_xor(v01l, 1), t23l = __shfl_xor(v23l, 1);
          int cbH = kg*65, cbL = 1040 + kg*65;
          if (!(l & 1)){
            ldsu[(cbH + m0 + 0)*4 + jj] = (v01h & 0xFFFFu) | (t01h << 16);
            ldsu[(cbH + m0 + 1)*4 + jj] = (v01h >> 16) | (t01h & 0xFFFF0000u);
            ldsu[(cbL + m0 + 0)*4 + jj] = (v01l & 0xFFFFu) | (t01l << 16);
            ldsu[(cbL + m0 + 1)*4 + jj] = (v01l >> 16) | (t01l & 0xFFFF0000u);
          } else {
            ldsu[(cbH + m0 + 2)*4 + jj] = (t23h & 0xFFFFu) | (v23h << 16);
            ldsu[(cbH + m0 + 3)*4 + jj] = (t23h >> 16) | (v23h & 0xFFFF0000u);
            ldsu[(cbL + m0 + 2)*4 + jj] = (t23l & 0xFFFFu) | (v23l << 16);
            ldsu[(cbL + m0 + 3)*4 + jj] = (t23l >> 16) | (v23l & 0xFFFF0000u);
          }
        }
      }
    }
    __syncthreads();

    for (int kt = 0; kt < 4; ++kt){
      bf16x8 Ah[2], Al[2];
      #pragma unroll
      for (int mtl=0;mtl<2;++mtl){
        int m = (mtw+mtl)*16 + r16;
        Ah[mtl] = *(const bf16x8*)(sAF + ((kt*4+quad)*65 + m)*8);
        Al[mtl] = *(const bf16x8*)(sAF + (1040 + (kt*4+quad)*65 + m)*8);
      }
      int ktAbs = sc2*4 + kt;                  // W3 k-tile (KT=8)
      const bf16x8* WfH = (const bf16x8*)W3F + (size_t)(ktAbs*8 + nth*4)*64 + l;
      const bf16x8* WfL = WfH + 8*8*64;
      #pragma unroll
      for (int ntl = 0; ntl < 4; ++ntl){
        bf16x8 Bh = WfH[ntl*64];
        bf16x8 Bl = WfL[ntl*64];
        f32x4 c0 = C3[ntl*2+0], c1 = C3[ntl*2+1];
        c0 = MFMA(Ah[0], Bh, c0); c1 = MFMA(Ah[1], Bh, c1);
        c0 = MFMA(Ah[0], Bl, c0); c1 = MFMA(Ah[1], Bl, c1);
        c0 = MFMA(Al[0], Bh, c0); c1 = MFMA(Al[1], Bh, c1);
        C3[ntl*2+0] = c0; C3[ntl*2+1] = c1;
      }
    }
  }

  // ---- C3 epilogue: h3 = C3 + b3 (NO elu) -> A4 ----
  __syncthreads();                             // all L3 reads done
  #pragma unroll
  for (int ntl = 0; ntl < 4; ++ntl){
    #pragma unroll
    for (int mtl = 0; mtl < 2; ++mtl){
      f32x4 v = C3[ntl*2+mtl];
      int n3 = (nth*4 + ntl)*16 + r16;         // 0..127
      float bv = b3[n3];
      ushort hi[4], lo[4];
      #pragma unroll
      for (int r=0;r<4;++r){
        float f = v[r] + bv;
        hi[r] = bf16_rne(f);
        float fh = __uint_as_float(((uint)hi[r])<<16);
        lo[r] = bf16_rne(f - fh);
      }
      int kg = n3 >> 3, j = n3 & 7, jj = (j & ~1) >> 1;
      int m0 = (mtw+mtl)*16 + quad*4;
      uint v01h = (uint)hi[0] | ((uint)hi[1]<<16);
      uint v23h = (uint)hi[2] | ((uint)hi[3]<<16);
      uint v01l = (uint)lo[0] | ((uint)lo[1]<<16);
      uint v23l = (uint)lo[2] | ((uint)lo[3]<<16);
      uint t01h = __shfl_xor(v01h, 1), t23h = __shfl_xor(v23h, 1);
      uint t01l = __shfl_xor(v01l, 1), t23l = __shfl_xor(v23l, 1);
      int cbH = kg*65, cbL = 1040 + kg*65;     // A4 region
      if (!(l & 1)){
        ldsu[(cbH + m0 + 0)*4 + jj] = (v01h & 0xFFFFu) | (t01h << 16);
        ldsu[(cbH + m0 + 1)*4 + jj] = (v01h >> 16) | (t01h & 0xFFFF0000u);
        ldsu[(cbL + m0 + 0)*4 + jj] = (v01l & 0xFFFFu) | (t01l << 16);
        ldsu[(cbL + m0 + 1)*4 + jj] = (v01l >> 16) | (t01l & 0xFFFF0000u);
      } else {
        ldsu[(cbH + m0 + 2)*4 + jj] = (t23h & 0xFFFFu) | (v23h << 16);
        ldsu[(cbH + m0 + 3)*4 + jj] = (t23h >> 16) | (v23h & 0xFFFF0000u);
        ldsu[(cbL + m0 + 2)*4 + jj] = (t23l & 0xFFFFu) | (v23l << 16);
        ldsu[(cbL + m0 + 3)*4 + jj] = (t23l >> 16) | (v23l & 0xFFFF0000u);
      }
    }
  }
  __syncthreads();

  // ---- layer 4: C4 = A4 @ W4 (K=128) ----
  f32x4 C4[8];
  #pragma unroll
  for (int i=0;i<8;++i) C4[i] = (f32x4)0.f;
  for (int kt = 0; kt < 4; ++kt){
    bf16x8 Ah[2], Al[2];
    #pragma unroll
    for (int mtl=0;mtl<2;++mtl){
      int m = (mtw+mtl)*16 + r16;
      Ah[mtl] = *(const bf16x8*)(sAF + ((kt*4+quad)*65 + m)*8);
      Al[mtl] = *(const bf16x8*)(sAF + (1040 + (kt*4+quad)*65 + m)*8);
    }
    const bf16x8* WfH = (const bf16x8*)W4F + (size_t)(kt*8 + nth*4)*64 + l;
    const bf16x8* WfL = WfH + 4*8*64;
    #pragma unroll
    for (int ntl = 0; ntl < 4; ++ntl){
      bf16x8 Bh = WfH[ntl*64];
      bf16x8 Bl = WfL[ntl*64];
      f32x4 c0 = C4[ntl*2+0], c1 = C4[ntl*2+1];
      c0 = MFMA(Ah[0], Bh, c0); c1 = MFMA(Ah[1], Bh, c1);
      c0 = MFMA(Ah[0], Bl, c0); c1 = MFMA(Ah[1], Bl, c1);
      c0 = MFMA(Al[0], Bh, c0); c1 = MFMA(Al[1], Bh, c1);
      C4[ntl*2+0] = c0; C4[ntl*2+1] = c1;
    }
  }

  // ---- layer 5: score = elu(C4+b4) . W5[:,t] ----
  float p[2][4] = {{0.f,0.f,0.f,0.f},{0.f,0.f,0.f,0.f}};
  #pragma unroll
  for (int ntl = 0; ntl < 4; ++ntl){
    int n4 = (nth*4 + ntl)*16 + r16;
    float bv = b4[n4];
    const float* w5r = W5 + n4*LL;
    #pragma unroll
    for (int mtl = 0; mtl < 2; ++mtl){
      f32x4 c = C4[ntl*2+mtl];
      #pragma unroll
      for (int r=0;r<4;++r){
        int m = (mtw+mtl)*16 + quad*4 + r;
        p[mtl][r] += elu_f(c[r] + bv) * w5r[sTy[m]];
      }
    }
  }
  #pragma unroll
  for (int d = 8; d >= 1; d >>= 1){
    #pragma unroll
    for (int mtl=0;mtl<2;++mtl)
      #pragma unroll
      for (int r=0;r<4;++r)
        p[mtl][r] += __shfl_down(p[mtl][r], d, 16);
  }
  if (r16 == 0){
    #pragma unroll
    for (int mtl=0;mtl<2;++mtl)
      #pragma unroll
      for (int r=0;r<4;++r)
        atomicAdd(&sScore[(mtw+mtl)*16 + quad*4 + r], p[mtl][r]);
  }
  __syncthreads();
  if (tid < 64){
    scores[e0 + tid] = sScore[tid] + b5[sTy[tid]];
    ebatch[e0 + tid] = sEb[tid];
  }
}

// ---------------------------------------------------------------------------
// Segment softmax / argmax passes (unchanged, verified)
// ---------------------------------------------------------------------------
__global__ void kInitSeg(unsigned* segmax, float* segsum, unsigned* gmax, int* gact){
  int b = blockIdx.x*blockDim.x + threadIdx.x;
  if (b < BB){ segmax[b] = ENC_NEG_INF; segsum[b] = 0.f; gmax[b] = ENC_NEG_INF; gact[b] = 0x7FFFFFFF; }
}

__global__ __launch_bounds__(256) void kSegMax(const float* __restrict__ scores,
                                               const int* __restrict__ eb,
                                               unsigned* __restrict__ segmax){
  __shared__ unsigned l[BB];
  for (int b = threadIdx.x; b < BB; b += 256) l[b] = 0u;
  __syncthreads();
  for (int e = blockIdx.x*256 + threadIdx.x; e < EE; e += gridDim.x*256)
    atomicMax(&l[eb[e]], enc_f(scores[e]));
  __syncthreads();
  for (int b = threadIdx.x; b < BB; b += 256)
    if (l[b]) atomicMax(&segmax[b], l[b]);
}

__global__ __launch_bounds__(256) void kExpSum(const float* __restrict__ scores,
                                               const int* __restrict__ eb,
                                               const unsigned* __restrict__ segmax,
                                               float* __restrict__ segsum,
                                               float* __restrict__ outprobs){
  __shared__ float l[BB];
  for (int b = threadIdx.x; b < BB; b += 256) l[b] = 0.f;
  __syncthreads();
  for (int e = blockIdx.x*256 + threadIdx.x; e < EE; e += gridDim.x*256){
    int b = eb[e];
    float ex = expf(scores[e] - dec_f(segmax[b]));
    outprobs[e] = ex;
    atomicAdd(&l[b], ex);
  }
  __syncthreads();
  for (int b = threadIdx.x; b < BB; b += 256)
    if (l[b] != 0.f) atomicAdd(&segsum[b], l[b]);
}

__global__ __launch_bounds__(256) void kProbMax(float* __restrict__ outprobs,
                                                const int* __restrict__ eb,
                                                const float* __restrict__ segsum,
                                                unsigned* __restrict__ gmax){
  __shared__ unsigned l[BB];
  for (int b = threadIdx.x; b < BB; b += 256) l[b] = 0u;
  __syncthreads();
  for (int e = blockIdx.x*256 + threadIdx.x; e < EE; e += gridDim.x*256){
    int b = eb[e];
    float p = outprobs[e] / segsum[b];
    outprobs[e] = p;
    atomicMax(&l[b], enc_f(p));
  }
  __syncthreads();
  for (int b = threadIdx.x; b < BB; b += 256)
    if (l[b]) atomicMax(&gmax[b], l[b]);
}

__global__ __launch_bounds__(256) void kArgMin(const float* __restrict__ outprobs,
                                               const int* __restrict__ eb,
                                               const unsigned* __restrict__ gmax,
                                               int* __restrict__ gact){
  __shared__ int l[BB];
  for (int b = threadIdx.x; b < BB; b += 256) l[b] = 0x7FFFFFFF;
  __syncthreads();
  for (int e = blockIdx.x*256 + threadIdx.x; e < EE; e += gridDim.x*256){
    int b = eb[e];
    if (enc_f(outprobs[e]) == gmax[b]) atomicMin(&l[b], e);
  }
  __syncthreads();
  for (int b = threadIdx.x; b < BB; b += 256)
    if (l[b] != 0x7FFFFFFF) atomicMin(&gact[b], l[b]);
}

__global__ void kFinal(const unsigned* __restrict__ gmax, const int* __restrict__ gact,
                       float* __restrict__ out){
  int b = threadIdx.x;
  if (b < BB){
    out[EE + b]      = dec_f(gmax[b]);
    out[EE + BB + b] = (float)gact[b];
  }
}

// ---------------------------------------------------------------------------
extern "C" void kernel_launch(void* const* d_in, const int* in_sizes, int n_in,
                              void* d_out, int out_size, void* d_ws, size_t ws_size,
                              hipStream_t stream){
  const float* r0 = (const float*)d_in[0];
  const float* r1 = (const float*)d_in[1];
  const float* W1 = (const float*)d_in[2];
  const float* b1 = (const float*)d_in[3];
  const float* W2 = (const float*)d_in[4];
  const float* b2 = (const float*)d_in[5];
  const float* W3 = (const float*)d_in[6];
  const float* b3 = (const float*)d_in[7];
  const float* W4 = (const float*)d_in[8];
  const float* b4 = (const float*)d_in[9];
  const float* W5 = (const float*)d_in[10];
  const float* b5 = (const float*)d_in[11];
  const int* edge_index = (const int*)d_in[12];
  const int* batch = (const int*)d_in[13];
  const int* y = (const int*)d_in[14];
  float* out = (float*)d_out;

  char* ws = (char*)d_ws;
  size_t off = 0;
  float*    scores = (float*)(ws + off);    off += (size_t)EE*4;
  int*      ebatch = (int*)(ws + off);      off += (size_t)EE*4;
  unsigned* segmax = (unsigned*)(ws + off); off += BB*4;
  float*    segsum = (float*)(ws + off);    off += BB*4;
  unsigned* gmax   = (unsigned*)(ws + off); off += BB*4;
  int*      gact   = (int*)(ws + off);      off += BB*4;
  off = (off + 511) & ~(size_t)511;
  ushort* repsF = (ushort*)(ws + off);      off += (size_t)NN*256*2;   // 51.2 MB
  ushort* W1F   = (ushort*)(ws + off);      off += (size_t)2*8*32*512*2;
  ushort* W2F   = (ushort*)(ws + off);      off += (size_t)2*16*16*512*2;
  ushort* W3F   = (ushort*)(ws + off);      off += (size_t)2*8*8*512*2;
  ushort* W4F   = (ushort*)(ws + off);      off += (size_t)2*4*8*512*2;

  kInitSeg<<<2, 256, 0, stream>>>(segmax, segsum, gmax, gact);
  kReps<<<(NN*16)/256, 256, 0, stream>>>(r0, r1, repsF);
  kPrepW<<<(8*32*64)/256, 256, 0, stream>>>(W1, 512, 8, 32, W1F);
  kPrepW<<<(16*16*64)/256, 256, 0, stream>>>(W2, 256, 16, 16, W2F);
  kPrepW<<<(8*8*64)/256, 256, 0, stream>>>(W3, 128, 8, 8, W3F);
  kPrepW<<<(4*8*64)/256, 256, 0, stream>>>(W4, 128, 4, 8, W4F);

  kMLP<<<EE/64, 256, 0, stream>>>(repsF, W1F, W2F, W3F, W4F,
                                  b1, b2, b3, b4, W5, b5,
                                  edge_index, batch, y, scores, ebatch);

  kSegMax <<<256, 256, 0, stream>>>(scores, ebatch, segmax);
  kExpSum <<<256, 256, 0, stream>>>(scores, ebatch, segmax, segsum, out);
  kProbMax<<<256, 256, 0, stream>>>(out, ebatch, segsum, gmax);
  kArgMin <<<256, 256, 0, stream>>>(out, ebatch, gmax, gact);
  kFinal  <<<1, 512, 0, stream>>>(gmax, gact, out);
}

// Round 5
// 2987.962 us; speedup vs baseline: 2.8615x; 1.3640x over previous
//
#include <hip/hip_runtime.h>
#include <hip/hip_bf16.h>
#include <cmath>

#define NN 100000   // nodes
#define EE 600000   // edges
#define BB 512      // graphs
#define LL 10       // labels
// H=128; L1 256->512, L2 512->256, L3 256->128, L4 128->128, L5 128->10 (col-picked)

typedef __attribute__((ext_vector_type(8))) short  bf16x8;
typedef __attribute__((ext_vector_type(4))) float  f32x4;
typedef unsigned int uint;
typedef unsigned short ushort;

__device__ __forceinline__ float elu_f(float x){ return x > 0.f ? x : expm1f(x); }

__device__ __forceinline__ ushort bf16_rne(float f){
  uint u = __float_as_uint(f);
  return (ushort)((u + 0x7FFFu + ((u >> 16) & 1u)) >> 16);
}

__device__ __forceinline__ f32x4 MFMA(bf16x8 a, bf16x8 b, f32x4 c){
  return __builtin_amdgcn_mfma_f32_16x16x32_bf16(a, b, c, 0, 0, 0);
}

// Monotone float<->uint encoding for atomic max/min on floats
__device__ __forceinline__ unsigned enc_f(float f){
  unsigned u = __float_as_uint(f);
  return (u & 0x80000000u) ? ~u : (u | 0x80000000u);
}
__device__ __forceinline__ float dec_f(unsigned u){
  return (u & 0x80000000u) ? __uint_as_float(u ^ 0x80000000u) : __uint_as_float(~u);
}
#define ENC_NEG_INF 0x007FFFFFu

// ---------------------------------------------------------------------------
// kReps: repsF[n] = 512B row: [hi bf16 k=0..127][lo bf16 k=0..127].
// ---------------------------------------------------------------------------
__global__ __launch_bounds__(256) void kReps(const float* __restrict__ r0,
                                             const float* __restrict__ r1,
                                             ushort* __restrict__ repsF){
  int gid = blockIdx.x*256 + threadIdx.x;          // N*16 threads
  int n = gid >> 4, k8 = gid & 15;
  const float4* a = (const float4*)(r0 + (size_t)n*128 + k8*8);
  const float4* b = (const float4*)(r1 + (size_t)n*128 + k8*8);
  float4 x0 = a[0], x1 = a[1], y0 = b[0], y1 = b[1];
  float d[8] = {x0.x-y0.x, x0.y-y0.y, x0.z-y0.z, x0.w-y0.w,
                x1.x-y1.x, x1.y-y1.y, x1.z-y1.z, x1.w-y1.w};
  ushort hi[8], lo[8];
  #pragma unroll
  for (int j=0;j<8;++j){
    hi[j] = bf16_rne(d[j]);
    float fh = __uint_as_float(((uint)hi[j])<<16);
    lo[j] = bf16_rne(d[j] - fh);
  }
  ushort* dh = repsF + (size_t)n*256 + k8*8;
  ushort* dl = dh + 128;
  #pragma unroll
  for (int j=0;j<8;++j){ dh[j] = hi[j]; dl[j] = lo[j]; }
}

// ---------------------------------------------------------------------------
// kPrepW: weight [K][N] fp32 -> MFMA-fragment bf16 hi/lo:
//   dst[part][kt][nt][lane][j] with k = kt*32+(l>>4)*8+j, n = nt*16+(l&15).
// ---------------------------------------------------------------------------
__global__ __launch_bounds__(256) void kPrepW(const float* __restrict__ W, int N,
                                              int KT, int NT, ushort* __restrict__ dst){
  int gid = blockIdx.x*256 + threadIdx.x;
  int total = KT*NT*64;
  if (gid >= total) return;
  int l = gid & 63, tile = gid >> 6;
  int kt = tile / NT, nt = tile % NT;
  int kbase = kt*32 + (l>>4)*8;
  int n = nt*16 + (l&15);
  int partStride = KT*NT*512;
  int base = tile*512 + l*8;
  #pragma unroll
  for (int j=0;j<8;++j){
    float f = W[(size_t)(kbase+j)*N + n];
    ushort h = bf16_rne(f);
    float fh = __uint_as_float(((uint)h)<<16);
    dst[base + j] = h;
    dst[partStride + base + j] = bf16_rne(f - fh);
  }
}

// ---------------------------------------------------------------------------
// LDS transpose helpers (wave-private buffer, [part][m(32)][col(64) pad 68]).
// xpose4: write 4 n-tiles x 2 m-tiles of C-frags (with bias, optional elu,
// hi/lo split) into the buffer.  Pair-packed b32 writes: <=2-way banks (free).
// readA: A-frag (8 consecutive cols at row m) as two b64 reads.
// ---------------------------------------------------------------------------
__device__ __forceinline__ void xpose4(ushort* sT, const f32x4* Cg,
                                       const float* __restrict__ biasPtr,
                                       bool doElu, int l){
  const int quad = l >> 4, r16 = l & 15;
  uint* ldsu = (uint*)sT;
  #pragma unroll
  for (int i = 0; i < 4; ++i){
    float bv = biasPtr[i*16 + r16];
    #pragma unroll
    for (int mtl = 0; mtl < 2; ++mtl){
      f32x4 v = Cg[i*2 + mtl];
      ushort hi[4], lo[4];
      #pragma unroll
      for (int r = 0; r < 4; ++r){
        float f = v[r] + bv;
        if (doElu) f = elu_f(f);
        hi[r] = bf16_rne(f);
        float fh = __uint_as_float(((uint)hi[r]) << 16);
        lo[r] = bf16_rne(f - fh);
      }
      uint v01h = (uint)hi[0] | ((uint)hi[1]<<16);
      uint v23h = (uint)hi[2] | ((uint)hi[3]<<16);
      uint v01l = (uint)lo[0] | ((uint)lo[1]<<16);
      uint v23l = (uint)lo[2] | ((uint)lo[3]<<16);
      uint t01h = __shfl_xor(v01h,1), t23h = __shfl_xor(v23h,1);
      uint t01l = __shfl_xor(v01l,1), t23l = __shfl_xor(v23l,1);
      int c2 = (i*16 + (r16 & ~1)) >> 1;      // uint col index 0..31
      int m0 = mtl*16 + quad*4;
      if (!(l & 1)){
        ldsu[(m0+0)*34 + c2]        = (v01h & 0xFFFFu) | (t01h << 16);
        ldsu[(m0+1)*34 + c2]        = (v01h >> 16) | (t01h & 0xFFFF0000u);
        ldsu[1088 + (m0+0)*34 + c2] = (v01l & 0xFFFFu) | (t01l << 16);
        ldsu[1088 + (m0+1)*34 + c2] = (v01l >> 16) | (t01l & 0xFFFF0000u);
      } else {
        ldsu[(m0+2)*34 + c2]        = (t23h & 0xFFFFu) | (v23h << 16);
        ldsu[(m0+3)*34 + c2]        = (t23h >> 16) | (v23h & 0xFFFF0000u);
        ldsu[1088 + (m0+2)*34 + c2] = (t23l & 0xFFFFu) | (v23l << 16);
        ldsu[1088 + (m0+3)*34 + c2] = (t23l >> 16) | (v23l & 0xFFFF0000u);
      }
    }
  }
}

__device__ __forceinline__ bf16x8 readA(const ushort* sT, int part, int m, int colBase){
  union { uint2 u[2]; bf16x8 v; } cvt;
  const ushort* p = sT + part*2176 + m*68 + colBase;
  cvt.u[0] = *(const uint2*)p;
  cvt.u[1] = *(const uint2*)(p + 4);
  return cvt.v;
}

// ---------------------------------------------------------------------------
// kMLP R5: wave-private pipeline. Block = 1 wave (64 threads) = 32 edges,
// ZERO __syncthreads.  A-frags from global repsF; inter-layer transposes via
// an 8.7 KB wave-private LDS buffer (same-wave lgkmcnt ordering only).
// launch_bounds(64,2): 256-VGPR cap, live set ~200 -> no spill (R3 lesson).
// ---------------------------------------------------------------------------
__global__ __launch_bounds__(64, 2) void kMLP(
    const ushort* __restrict__ repsF,
    const ushort* __restrict__ W1F, const ushort* __restrict__ W2F,
    const ushort* __restrict__ W3F, const ushort* __restrict__ W4F,
    const float* __restrict__ b1, const float* __restrict__ b2,
    const float* __restrict__ b3, const float* __restrict__ b4,
    const float* __restrict__ W5, const float* __restrict__ b5,
    const int* __restrict__ edge_index, const int* __restrict__ batch,
    const int* __restrict__ y,
    float* __restrict__ scores, int* __restrict__ ebatch)
{
  __shared__ __align__(16) ushort sT[2*32*68];   // 8704 B, wave-private
  __shared__ int sTy[32];

  const int l = threadIdx.x;
  const int quad = l >> 4, r16 = l & 15;
  const int e0 = blockIdx.x * 32;

  if (l < 32){
    int s = edge_index[e0 + l];
    int eb = batch[s];
    ebatch[e0 + l] = eb;
    sTy[l] = y[eb];
  }

  // per-lane node row pointers (lane r16 owns edge m=r16 of each m-tile)
  const int eA0 = e0 + r16, eA1 = e0 + 16 + r16;
  const ushort* aS0 = repsF + (size_t)edge_index[eA0]*256;
  const ushort* aS1 = repsF + (size_t)edge_index[eA1]*256;
  const ushort* aD0 = repsF + (size_t)edge_index[EE + eA0]*256;
  const ushort* aD1 = repsF + (size_t)edge_index[EE + eA1]*256;

  // ---- layers 1+2: h1 (N=512) in 8 chunks of 64 cols; C2 accumulates ----
  f32x4 C2[32];                      // 16 n-tiles x 2 m-tiles (128 VGPR)
  #pragma unroll
  for (int i=0;i<32;++i) C2[i] = (f32x4)0.f;

  #pragma unroll 1
  for (int chunk = 0; chunk < 8; ++chunk){
    f32x4 C1[8];                     // 4 n-tiles x 2 m-tiles
    #pragma unroll
    for (int i=0;i<8;++i) C1[i] = (f32x4)0.f;

    #pragma unroll
    for (int hk = 0; hk < 8; ++hk){  // K=256: src k-tiles 0..3, dst 4..7
      const ushort* p0 = (hk < 4) ? aS0 : aD0;
      const ushort* p1 = (hk < 4) ? aS1 : aD1;
      const int ko = (hk & 3)*32 + quad*8;
      bf16x8 Ah0 = *(const bf16x8*)(p0 + ko);
      bf16x8 Al0 = *(const bf16x8*)(p0 + 128 + ko);
      bf16x8 Ah1 = *(const bf16x8*)(p1 + ko);
      bf16x8 Al1 = *(const bf16x8*)(p1 + 128 + ko);
      const bf16x8* WfH = (const bf16x8*)W1F + ((size_t)hk*32 + chunk*4)*64 + l;
      const bf16x8* WfL = WfH + 8*32*64;
      #pragma unroll
      for (int i = 0; i < 4; ++i){
        bf16x8 Bh = WfH[i*64], Bl = WfL[i*64];
        f32x4 c0 = C1[i*2], c1 = C1[i*2+1];
        c0 = MFMA(Ah0, Bh, c0); c1 = MFMA(Ah1, Bh, c1);
        c0 = MFMA(Ah0, Bl, c0); c1 = MFMA(Ah1, Bl, c1);
        c0 = MFMA(Al0, Bh, c0); c1 = MFMA(Al1, Bh, c1);
        C1[i*2] = c0; C1[i*2+1] = c1;
      }
    }

    // h1 chunk -> LDS (elu+b1, hi/lo) ; then layer-2 partial over this K-slice
    xpose4(sT, C1, b1 + chunk*64, true, l);

    #pragma unroll
    for (int kt2 = 0; kt2 < 2; ++kt2){
      bf16x8 Ah[2], Al[2];
      #pragma unroll
      for (int mtl = 0; mtl < 2; ++mtl){
        int m = mtl*16 + r16;
        Ah[mtl] = readA(sT, 0, m, kt2*32 + quad*8);
        Al[mtl] = readA(sT, 1, m, kt2*32 + quad*8);
      }
      const bf16x8* WfH = (const bf16x8*)W2F + ((size_t)(chunk*2 + kt2)*16)*64 + l;
      const bf16x8* WfL = WfH + 16*16*64;
      #pragma unroll
      for (int nt = 0; nt < 16; ++nt){
        bf16x8 Bh = WfH[nt*64], Bl = WfL[nt*64];
        f32x4 c0 = C2[nt*2], c1 = C2[nt*2+1];
        c0 = MFMA(Ah[0], Bh, c0); c1 = MFMA(Ah[1], Bh, c1);
        c0 = MFMA(Ah[0], Bl, c0); c1 = MFMA(Ah[1], Bl, c1);
        c0 = MFMA(Al[0], Bh, c0); c1 = MFMA(Al[1], Bh, c1);
        C2[nt*2] = c0; C2[nt*2+1] = c1;
      }
    }
  }

  // ---- layer 3: h2 (K=256) in 4 slices of 64 cols ----
  f32x4 C3[16];
  #pragma unroll
  for (int i=0;i<16;++i) C3[i] = (f32x4)0.f;
  #pragma unroll 1
  for (int slice = 0; slice < 4; ++slice){
    xpose4(sT, &C2[slice*8], b2 + slice*64, true, l);
    #pragma unroll
    for (int kt = 0; kt < 2; ++kt){
      bf16x8 Ah[2], Al[2];
      #pragma unroll
      for (int mtl = 0; mtl < 2; ++mtl){
        int m = mtl*16 + r16;
        Ah[mtl] = readA(sT, 0, m, kt*32 + quad*8);
        Al[mtl] = readA(sT, 1, m, kt*32 + quad*8);
      }
      const bf16x8* WfH = (const bf16x8*)W3F + ((size_t)(slice*2 + kt)*8)*64 + l;
      const bf16x8* WfL = WfH + 8*8*64;
      #pragma unroll
      for (int nt = 0; nt < 8; ++nt){
        bf16x8 Bh = WfH[nt*64], Bl = WfL[nt*64];
        f32x4 c0 = C3[nt*2], c1 = C3[nt*2+1];
        c0 = MFMA(Ah[0], Bh, c0); c1 = MFMA(Ah[1], Bh, c1);
        c0 = MFMA(Ah[0], Bl, c0); c1 = MFMA(Ah[1], Bl, c1);
        c0 = MFMA(Al[0], Bh, c0); c1 = MFMA(Al[1], Bh, c1);
        C3[nt*2] = c0; C3[nt*2+1] = c1;
      }
    }
  }

  // ---- layer 4: h3 (K=128) in 2 slices of 64 cols (h3 = C3+b3, NO elu) ----
  f32x4 C4[16];
  #pragma unroll
  for (int i=0;i<16;++i) C4[i] = (f32x4)0.f;
  #pragma unroll 1
  for (int slice = 0; slice < 2; ++slice){
    xpose4(sT, &C3[slice*8], b3 + slice*64, false, l);
    #pragma unroll
    for (int kt = 0; kt < 2; ++kt){
      bf16x8 Ah[2], Al[2];
      #pragma unroll
      for (int mtl = 0; mtl < 2; ++mtl){
        int m = mtl*16 + r16;
        Ah[mtl] = readA(sT, 0, m, kt*32 + quad*8);
        Al[mtl] = readA(sT, 1, m, kt*32 + quad*8);
      }
      const bf16x8* WfH = (const bf16x8*)W4F + ((size_t)(slice*2 + kt)*8)*64 + l;
      const bf16x8* WfL = WfH + 4*8*64;
      #pragma unroll
      for (int nt = 0; nt < 8; ++nt){
        bf16x8 Bh = WfH[nt*64], Bl = WfL[nt*64];
        f32x4 c0 = C4[nt*2], c1 = C4[nt*2+1];
        c0 = MFMA(Ah[0], Bh, c0); c1 = MFMA(Ah[1], Bh, c1);
        c0 = MFMA(Ah[0], Bl, c0); c1 = MFMA(Ah[1], Bl, c1);
        c0 = MFMA(Al[0], Bh, c0); c1 = MFMA(Al[1], Bh, c1);
        C4[nt*2] = c0; C4[nt*2+1] = c1;
      }
    }
  }

  // ---- layer 5: score = elu(C4+b4) . W5[:,t] + b5[t] ----
  int tvals[2][4];
  #pragma unroll
  for (int mtl=0;mtl<2;++mtl)
    #pragma unroll
    for (int r=0;r<4;++r) tvals[mtl][r] = sTy[mtl*16 + quad*4 + r];

  float p[2][4] = {{0.f,0.f,0.f,0.f},{0.f,0.f,0.f,0.f}};
  #pragma unroll
  for (int nt = 0; nt < 8; ++nt){
    int n4 = nt*16 + r16;
    float bv = b4[n4];
    const float* w5r = W5 + n4*LL;
    #pragma unroll
    for (int mtl = 0; mtl < 2; ++mtl){
      f32x4 c = C4[nt*2+mtl];
      #pragma unroll
      for (int r=0;r<4;++r)
        p[mtl][r] += elu_f(c[r] + bv) * w5r[tvals[mtl][r]];
    }
  }
  #pragma unroll
  for (int d = 8; d >= 1; d >>= 1){
    #pragma unroll
    for (int mtl=0;mtl<2;++mtl)
      #pragma unroll
      for (int r=0;r<4;++r)
        p[mtl][r] += __shfl_down(p[mtl][r], d, 16);
  }
  if (r16 == 0){
    #pragma unroll
    for (int mtl=0;mtl<2;++mtl)
      #pragma unroll
      for (int r=0;r<4;++r){
        int m = mtl*16 + quad*4 + r;
        scores[e0 + m] = p[mtl][r] + b5[tvals[mtl][r]];
      }
  }
}

// ---------------------------------------------------------------------------
// Segment softmax / argmax passes (unchanged, verified)
// ---------------------------------------------------------------------------
__global__ void kInitSeg(unsigned* segmax, float* segsum, unsigned* gmax, int* gact){
  int b = blockIdx.x*blockDim.x + threadIdx.x;
  if (b < BB){ segmax[b] = ENC_NEG_INF; segsum[b] = 0.f; gmax[b] = ENC_NEG_INF; gact[b] = 0x7FFFFFFF; }
}

__global__ __launch_bounds__(256) void kSegMax(const float* __restrict__ scores,
                                               const int* __restrict__ eb,
                                               unsigned* __restrict__ segmax){
  __shared__ unsigned l[BB];
  for (int b = threadIdx.x; b < BB; b += 256) l[b] = 0u;
  __syncthreads();
  for (int e = blockIdx.x*256 + threadIdx.x; e < EE; e += gridDim.x*256)
    atomicMax(&l[eb[e]], enc_f(scores[e]));
  __syncthreads();
  for (int b = threadIdx.x; b < BB; b += 256)
    if (l[b]) atomicMax(&segmax[b], l[b]);
}

__global__ __launch_bounds__(256) void kExpSum(const float* __restrict__ scores,
                                               const int* __restrict__ eb,
                                               const unsigned* __restrict__ segmax,
                                               float* __restrict__ segsum,
                                               float* __restrict__ outprobs){
  __shared__ float l[BB];
  for (int b = threadIdx.x; b < BB; b += 256) l[b] = 0.f;
  __syncthreads();
  for (int e = blockIdx.x*256 + threadIdx.x; e < EE; e += gridDim.x*256){
    int b = eb[e];
    float ex = expf(scores[e] - dec_f(segmax[b]));
    outprobs[e] = ex;
    atomicAdd(&l[b], ex);
  }
  __syncthreads();
  for (int b = threadIdx.x; b < BB; b += 256)
    if (l[b] != 0.f) atomicAdd(&segsum[b], l[b]);
}

__global__ __launch_bounds__(256) void kProbMax(float* __restrict__ outprobs,
                                                const int* __restrict__ eb,
                                                const float* __restrict__ segsum,
                                                unsigned* __restrict__ gmax){
  __shared__ unsigned l[BB];
  for (int b = threadIdx.x; b < BB; b += 256) l[b] = 0u;
  __syncthreads();
  for (int e = blockIdx.x*256 + threadIdx.x; e < EE; e += gridDim.x*256){
    int b = eb[e];
    float p = outprobs[e] / segsum[b];
    outprobs[e] = p;
    atomicMax(&l[b], enc_f(p));
  }
  __syncthreads();
  for (int b = threadIdx.x; b < BB; b += 256)
    if (l[b]) atomicMax(&gmax[b], l[b]);
}

__global__ __launch_bounds__(256) void kArgMin(const float* __restrict__ outprobs,
                                               const int* __restrict__ eb,
                                               const unsigned* __restrict__ gmax,
                                               int* __restrict__ gact){
  __shared__ int l[BB];
  for (int b = threadIdx.x; b < BB; b += 256) l[b] = 0x7FFFFFFF;
  __syncthreads();
  for (int e = blockIdx.x*256 + threadIdx.x; e < EE; e += gridDim.x*256){
    int b = eb[e];
    if (enc_f(outprobs[e]) == gmax[b]) atomicMin(&l[b], e);
  }
  __syncthreads();
  for (int b = threadIdx.x; b < BB; b += 256)
    if (l[b] != 0x7FFFFFFF) atomicMin(&gact[b], l[b]);
}

__global__ void kFinal(const unsigned* __restrict__ gmax, const int* __restrict__ gact,
                       float* __restrict__ out){
  int b = threadIdx.x;
  if (b < BB){
    out[EE + b]      = dec_f(gmax[b]);
    out[EE + BB + b] = (float)gact[b];
  }
}

// ---------------------------------------------------------------------------
extern "C" void kernel_launch(void* const* d_in, const int* in_sizes, int n_in,
                              void* d_out, int out_size, void* d_ws, size_t ws_size,
                              hipStream_t stream){
  const float* r0 = (const float*)d_in[0];
  const float* r1 = (const float*)d_in[1];
  const float* W1 = (const float*)d_in[2];
  const float* b1 = (const float*)d_in[3];
  const float* W2 = (const float*)d_in[4];
  const float* b2 = (const float*)d_in[5];
  const float* W3 = (const float*)d_in[6];
  const float* b3 = (const float*)d_in[7];
  const float* W4 = (const float*)d_in[8];
  const float* b4 = (const float*)d_in[9];
  const float* W5 = (const float*)d_in[10];
  const float* b5 = (const float*)d_in[11];
  const int* edge_index = (const int*)d_in[12];
  const int* batch = (const int*)d_in[13];
  const int* y = (const int*)d_in[14];
  float* out = (float*)d_out;

  char* ws = (char*)d_ws;
  size_t off = 0;
  float*    scores = (float*)(ws + off);    off += (size_t)EE*4;
  int*      ebatch = (int*)(ws + off);      off += (size_t)EE*4;
  unsigned* segmax = (unsigned*)(ws + off); off += BB*4;
  float*    segsum = (float*)(ws + off);    off += BB*4;
  unsigned* gmax   = (unsigned*)(ws + off); off += BB*4;
  int*      gact   = (int*)(ws + off);      off += BB*4;
  off = (off + 511) & ~(size_t)511;
  ushort* repsF = (ushort*)(ws + off);      off += (size_t)NN*256*2;   // 51.2 MB
  ushort* W1F   = (ushort*)(ws + off);      off += (size_t)2*8*32*512*2;
  ushort* W2F   = (ushort*)(ws + off);      off += (size_t)2*16*16*512*2;
  ushort* W3F   = (ushort*)(ws + off);      off += (size_t)2*8*8*512*2;
  ushort* W4F   = (ushort*)(ws + off);      off += (size_t)2*4*8*512*2;

  kInitSeg<<<2, 256, 0, stream>>>(segmax, segsum, gmax, gact);
  kReps<<<(NN*16)/256, 256, 0, stream>>>(r0, r1, repsF);
  kPrepW<<<(8*32*64)/256, 256, 0, stream>>>(W1, 512, 8, 32, W1F);
  kPrepW<<<(16*16*64)/256, 256, 0, stream>>>(W2, 256, 16, 16, W2F);
  kPrepW<<<(8*8*64)/256, 256, 0, stream>>>(W3, 128, 8, 8, W3F);
  kPrepW<<<(4*8*64)/256, 256, 0, stream>>>(W4, 128, 4, 8, W4F);

  kMLP<<<EE/32, 64, 0, stream>>>(repsF, W1F, W2F, W3F, W4F,
                                 b1, b2, b3, b4, W5, b5,
                                 edge_index, batch, y, scores, ebatch);

  kSegMax <<<256, 256, 0, stream>>>(scores, ebatch, segmax);
  kExpSum <<<256, 256, 0, stream>>>(scores, ebatch, segmax, segsum, out);
  kProbMax<<<256, 256, 0, stream>>>(out, ebatch, segsum, gmax);
  kArgMin <<<256, 256, 0, stream>>>(out, ebatch, gmax, gact);
  kFinal  <<<1, 512, 0, stream>>>(gmax, gact, out);
}

// Round 6
// 2901.024 us; speedup vs baseline: 2.9473x; 1.0300x over previous
//
#include <hip/hip_runtime.h>
#include <hip/hip_bf16.h>
#include <cmath>

#define NN 100000   // nodes
#define EE 600000   // edges
#define BB 512      // graphs
#define LL 10       // labels
// H=128; L1 256->512, L2 512->256, L3 256->128, L4 128->128, L5 128->10 (col-picked)

typedef __attribute__((ext_vector_type(8))) short  bf16x8;
typedef __attribute__((ext_vector_type(4))) float  f32x4;
typedef unsigned int uint;
typedef unsigned short ushort;

__device__ __forceinline__ float elu_f(float x){ return x > 0.f ? x : expm1f(x); }

__device__ __forceinline__ ushort bf16_rne(float f){
  uint u = __float_as_uint(f);
  return (ushort)((u + 0x7FFFu + ((u >> 16) & 1u)) >> 16);
}

__device__ __forceinline__ f32x4 MFMA(bf16x8 a, bf16x8 b, f32x4 c){
  return __builtin_amdgcn_mfma_f32_16x16x32_bf16(a, b, c, 0, 0, 0);
}

// Monotone float<->uint encoding for atomic max/min on floats
__device__ __forceinline__ unsigned enc_f(float f){
  unsigned u = __float_as_uint(f);
  return (u & 0x80000000u) ? ~u : (u | 0x80000000u);
}
__device__ __forceinline__ float dec_f(unsigned u){
  return (u & 0x80000000u) ? __uint_as_float(u ^ 0x80000000u) : __uint_as_float(~u);
}
#define ENC_NEG_INF 0x007FFFFFu

// ---------------------------------------------------------------------------
// kReps: repsF[n] = 512B row: [hi bf16 k=0..127][lo bf16 k=0..127].
// ---------------------------------------------------------------------------
__global__ __launch_bounds__(256) void kReps(const float* __restrict__ r0,
                                             const float* __restrict__ r1,
                                             ushort* __restrict__ repsF){
  int gid = blockIdx.x*256 + threadIdx.x;          // N*16 threads
  int n = gid >> 4, k8 = gid & 15;
  const float4* a = (const float4*)(r0 + (size_t)n*128 + k8*8);
  const float4* b = (const float4*)(r1 + (size_t)n*128 + k8*8);
  float4 x0 = a[0], x1 = a[1], y0 = b[0], y1 = b[1];
  float d[8] = {x0.x-y0.x, x0.y-y0.y, x0.z-y0.z, x0.w-y0.w,
                x1.x-y1.x, x1.y-y1.y, x1.z-y1.z, x1.w-y1.w};
  ushort hi[8], lo[8];
  #pragma unroll
  for (int j=0;j<8;++j){
    hi[j] = bf16_rne(d[j]);
    float fh = __uint_as_float(((uint)hi[j])<<16);
    lo[j] = bf16_rne(d[j] - fh);
  }
  ushort* dh = repsF + (size_t)n*256 + k8*8;
  ushort* dl = dh + 128;
  #pragma unroll
  for (int j=0;j<8;++j){ dh[j] = hi[j]; dl[j] = lo[j]; }
}

// ---------------------------------------------------------------------------
// kPrepW: weight [K][N] fp32 -> MFMA-fragment bf16 hi/lo:
//   dst[part][kt][nt][lane][j] with k = kt*32+(l>>4)*8+j, n = nt*16+(l&15).
// ---------------------------------------------------------------------------
__global__ __launch_bounds__(256) void kPrepW(const float* __restrict__ W, int N,
                                              int KT, int NT, ushort* __restrict__ dst){
  int gid = blockIdx.x*256 + threadIdx.x;
  int total = KT*NT*64;
  if (gid >= total) return;
  int l = gid & 63, tile = gid >> 6;
  int kt = tile / NT, nt = tile % NT;
  int kbase = kt*32 + (l>>4)*8;
  int n = nt*16 + (l&15);
  int partStride = KT*NT*512;
  int base = tile*512 + l*8;
  #pragma unroll
  for (int j=0;j<8;++j){
    float f = W[(size_t)(kbase+j)*N + n];
    ushort h = bf16_rne(f);
    float fh = __uint_as_float(((uint)h)<<16);
    dst[base + j] = h;
    dst[partStride + base + j] = bf16_rne(f - fh);
  }
}

// ---------------------------------------------------------------------------
// LDS transpose helpers (wave-private region, [part][m(32)][col(64) pad 68]).
// xposeN: write NTILES n-tiles x 2 m-tiles of C-frags (bias, optional elu,
// hi/lo split).  Pair-packed b32 writes: <=2-way banks (free).
// readA: A-frag (8 consecutive cols at row m) as two b64 reads.
// ---------------------------------------------------------------------------
template<int NTILES>
__device__ __forceinline__ void xposeN(ushort* sT, const f32x4* Cg,
                                       const float* __restrict__ biasPtr,
                                       bool doElu, int l){
  const int quad = l >> 4, r16 = l & 15;
  uint* ldsu = (uint*)sT;
  #pragma unroll
  for (int i = 0; i < NTILES; ++i){
    float bv = biasPtr[i*16 + r16];
    #pragma unroll
    for (int mtl = 0; mtl < 2; ++mtl){
      f32x4 v = Cg[i*2 + mtl];
      ushort hi[4], lo[4];
      #pragma unroll
      for (int r = 0; r < 4; ++r){
        float f = v[r] + bv;
        if (doElu) f = elu_f(f);
        hi[r] = bf16_rne(f);
        float fh = __uint_as_float(((uint)hi[r]) << 16);
        lo[r] = bf16_rne(f - fh);
      }
      uint v01h = (uint)hi[0] | ((uint)hi[1]<<16);
      uint v23h = (uint)hi[2] | ((uint)hi[3]<<16);
      uint v01l = (uint)lo[0] | ((uint)lo[1]<<16);
      uint v23l = (uint)lo[2] | ((uint)lo[3]<<16);
      uint t01h = __shfl_xor(v01h,1), t23h = __shfl_xor(v23h,1);
      uint t01l = __shfl_xor(v01l,1), t23l = __shfl_xor(v23l,1);
      int c2 = (i*16 + (r16 & ~1)) >> 1;      // uint col index
      int m0 = mtl*16 + quad*4;
      if (!(l & 1)){
        ldsu[(m0+0)*34 + c2]        = (v01h & 0xFFFFu) | (t01h << 16);
        ldsu[(m0+1)*34 + c2]        = (v01h >> 16) | (t01h & 0xFFFF0000u);
        ldsu[1088 + (m0+0)*34 + c2] = (v01l & 0xFFFFu) | (t01l << 16);
        ldsu[1088 + (m0+1)*34 + c2] = (v01l >> 16) | (t01l & 0xFFFF0000u);
      } else {
        ldsu[(m0+2)*34 + c2]        = (t23h & 0xFFFFu) | (v23h << 16);
        ldsu[(m0+3)*34 + c2]        = (t23h >> 16) | (v23h & 0xFFFF0000u);
        ldsu[1088 + (m0+2)*34 + c2] = (t23l & 0xFFFFu) | (v23l << 16);
        ldsu[1088 + (m0+3)*34 + c2] = (t23l >> 16) | (v23l & 0xFFFF0000u);
      }
    }
  }
}

__device__ __forceinline__ bf16x8 readA(const ushort* region, int part, int m, int colBase){
  union { uint2 u[2]; bf16x8 v; } cvt;
  const ushort* p = region + part*2176 + m*68 + colBase;
  cvt.u[0] = *(const uint2*)p;
  cvt.u[1] = *(const uint2*)(p + 4);
  return cvt.v;
}

// ---------------------------------------------------------------------------
// kMLP R6: wave-private zero-barrier pipeline (R5) with the register peak
// engineered below the 256 cap at EVERY phase (R5 spilled 2.45 GB scratch:
// acc 160 + arch 128 = 288 > 256):
//  - L1 in 32-col slices: C1[4]=16 acc; L1/L2 peak = C2(128)+C1(16)=144.
//  - L3: xpose TWO h2 slices into two LDS regions BEFORE C3 MFMAs start,
//    so C2 partially dies first: peak = C2(64)+C3(64)=128 (was 192).
//  - L4: C3(64)+C4(64)=128.
// Two 8704 B LDS regions; 17.5 KB/block -> LDS allows >8 blocks/CU;
// VGPR allows 8 waves/CU (launch_bounds(64,2), 256-VGPR cap).
// ---------------------------------------------------------------------------
__global__ __launch_bounds__(64, 2) void kMLP(
    const ushort* __restrict__ repsF,
    const ushort* __restrict__ W1F, const ushort* __restrict__ W2F,
    const ushort* __restrict__ W3F, const ushort* __restrict__ W4F,
    const float* __restrict__ b1, const float* __restrict__ b2,
    const float* __restrict__ b3, const float* __restrict__ b4,
    const float* __restrict__ W5, const float* __restrict__ b5,
    const int* __restrict__ edge_index, const int* __restrict__ batch,
    const int* __restrict__ y,
    float* __restrict__ scores, int* __restrict__ ebatch)
{
  __shared__ __align__(16) ushort sT0[2*32*68];   // region 0: 8704 B
  __shared__ __align__(16) ushort sT1[2*32*68];   // region 1: 8704 B
  __shared__ int sTy[32];

  const int l = threadIdx.x;
  const int quad = l >> 4, r16 = l & 15;
  const int e0 = blockIdx.x * 32;

  if (l < 32){
    int s = edge_index[e0 + l];
    int eb = batch[s];
    ebatch[e0 + l] = eb;
    sTy[l] = y[eb];
  }

  // per-lane node row pointers (lane r16 owns edge m=r16 of each m-tile)
  const int eA0 = e0 + r16, eA1 = e0 + 16 + r16;
  const ushort* aS0 = repsF + (size_t)edge_index[eA0]*256;
  const ushort* aS1 = repsF + (size_t)edge_index[eA1]*256;
  const ushort* aD0 = repsF + (size_t)edge_index[EE + eA0]*256;
  const ushort* aD1 = repsF + (size_t)edge_index[EE + eA1]*256;

  // ---- layers 1+2: h1 (N=512) in 16 slices of 32 cols; C2 accumulates ----
  f32x4 C2[32];                      // 16 n-tiles x 2 m-tiles (128 acc regs)
  #pragma unroll
  for (int i=0;i<32;++i) C2[i] = (f32x4)0.f;

  #pragma unroll 1
  for (int sl = 0; sl < 16; ++sl){
    ushort* reg = (sl & 1) ? sT1 : sT0;
    f32x4 C1[4];                     // 2 n-tiles x 2 m-tiles (16 acc regs)
    #pragma unroll
    for (int i=0;i<4;++i) C1[i] = (f32x4)0.f;

    #pragma unroll
    for (int hk = 0; hk < 8; ++hk){  // K=256: src k-tiles 0..3, dst 4..7
      const ushort* p0 = (hk < 4) ? aS0 : aD0;
      const ushort* p1 = (hk < 4) ? aS1 : aD1;
      const int ko = (hk & 3)*32 + quad*8;
      bf16x8 Ah0 = *(const bf16x8*)(p0 + ko);
      bf16x8 Al0 = *(const bf16x8*)(p0 + 128 + ko);
      bf16x8 Ah1 = *(const bf16x8*)(p1 + ko);
      bf16x8 Al1 = *(const bf16x8*)(p1 + 128 + ko);
      const bf16x8* WfH = (const bf16x8*)W1F + ((size_t)hk*32 + sl*2)*64 + l;
      const bf16x8* WfL = WfH + 8*32*64;
      #pragma unroll
      for (int i = 0; i < 2; ++i){
        bf16x8 Bh = WfH[i*64], Bl = WfL[i*64];
        f32x4 c0 = C1[i*2], c1 = C1[i*2+1];
        c0 = MFMA(Ah0, Bh, c0); c1 = MFMA(Ah1, Bh, c1);
        c0 = MFMA(Ah0, Bl, c0); c1 = MFMA(Ah1, Bl, c1);
        c0 = MFMA(Al0, Bh, c0); c1 = MFMA(Al1, Bh, c1);
        C1[i*2] = c0; C1[i*2+1] = c1;
      }
    }

    // h1 slice -> LDS (elu+b1, hi/lo) ; then layer-2 partial (K=32, kt=sl)
    xposeN<2>(reg, C1, b1 + sl*32, true, l);

    bf16x8 Ah[2], Al[2];
    #pragma unroll
    for (int mtl = 0; mtl < 2; ++mtl){
      int m = mtl*16 + r16;
      Ah[mtl] = readA(reg, 0, m, quad*8);
      Al[mtl] = readA(reg, 1, m, quad*8);
    }
    const bf16x8* WfH = (const bf16x8*)W2F + ((size_t)sl*16)*64 + l;
    const bf16x8* WfL = WfH + 16*16*64;
    #pragma unroll
    for (int nt = 0; nt < 16; ++nt){
      bf16x8 Bh = WfH[nt*64], Bl = WfL[nt*64];
      f32x4 c0 = C2[nt*2], c1 = C2[nt*2+1];
      c0 = MFMA(Ah[0], Bh, c0); c1 = MFMA(Ah[1], Bh, c1);
      c0 = MFMA(Ah[0], Bl, c0); c1 = MFMA(Ah[1], Bl, c1);
      c0 = MFMA(Al[0], Bh, c0); c1 = MFMA(Al[1], Bh, c1);
      C2[nt*2] = c0; C2[nt*2+1] = c1;
    }
  }

  // ---- layer 3: h2 (K=256) in 2 halves of 128 cols (2 slices per half) ----
  // xpose both slices of a half FIRST -> half of C2 dies before C3 MFMAs.
  f32x4 C3[16];
  #pragma unroll
  for (int i=0;i<16;++i) C3[i] = (f32x4)0.f;
  #pragma unroll 1
  for (int half = 0; half < 2; ++half){
    xposeN<4>(sT0, &C2[half*16],     b2 + half*128,      true, l);
    xposeN<4>(sT1, &C2[half*16 + 8], b2 + half*128 + 64, true, l);
    #pragma unroll
    for (int kt2 = 0; kt2 < 4; ++kt2){
      const ushort* reg = (kt2 & 2) ? sT1 : sT0;
      int colBase = (kt2 & 1)*32 + quad*8;
      bf16x8 Ah[2], Al[2];
      #pragma unroll
      for (int mtl = 0; mtl < 2; ++mtl){
        int m = mtl*16 + r16;
        Ah[mtl] = readA(reg, 0, m, colBase);
        Al[mtl] = readA(reg, 1, m, colBase);
      }
      int kt = half*4 + kt2;                 // W3 k-tile (KT=8)
      const bf16x8* WfH = (const bf16x8*)W3F + ((size_t)kt*8)*64 + l;
      const bf16x8* WfL = WfH + 8*8*64;
      #pragma unroll
      for (int nt = 0; nt < 8; ++nt){
        bf16x8 Bh = WfH[nt*64], Bl = WfL[nt*64];
        f32x4 c0 = C3[nt*2], c1 = C3[nt*2+1];
        c0 = MFMA(Ah[0], Bh, c0); c1 = MFMA(Ah[1], Bh, c1);
        c0 = MFMA(Ah[0], Bl, c0); c1 = MFMA(Ah[1], Bl, c1);
        c0 = MFMA(Al[0], Bh, c0); c1 = MFMA(Al[1], Bh, c1);
        C3[nt*2] = c0; C3[nt*2+1] = c1;
      }
    }
  }

  // ---- layer 4: h3 (K=128; h3 = C3+b3, NO elu) ----
  f32x4 C4[16];
  #pragma unroll
  for (int i=0;i<16;++i) C4[i] = (f32x4)0.f;
  xposeN<4>(sT0, &C3[0], b3,      false, l);
  xposeN<4>(sT1, &C3[8], b3 + 64, false, l);
  #pragma unroll 1
  for (int kt = 0; kt < 4; ++kt){
    const ushort* reg = (kt & 2) ? sT1 : sT0;
    int colBase = (kt & 1)*32 + quad*8;
    bf16x8 Ah[2], Al[2];
    #pragma unroll
    for (int mtl = 0; mtl < 2; ++mtl){
      int m = mtl*16 + r16;
      Ah[mtl] = readA(reg, 0, m, colBase);
      Al[mtl] = readA(reg, 1, m, colBase);
    }
    const bf16x8* WfH = (const bf16x8*)W4F + ((size_t)kt*8)*64 + l;
    const bf16x8* WfL = WfH + 4*8*64;
    #pragma unroll
    for (int nt = 0; nt < 8; ++nt){
      bf16x8 Bh = WfH[nt*64], Bl = WfL[nt*64];
      f32x4 c0 = C4[nt*2], c1 = C4[nt*2+1];
      c0 = MFMA(Ah[0], Bh, c0); c1 = MFMA(Ah[1], Bh, c1);
      c0 = MFMA(Ah[0], Bl, c0); c1 = MFMA(Ah[1], Bl, c1);
      c0 = MFMA(Al[0], Bh, c0); c1 = MFMA(Al[1], Bh, c1);
      C4[nt*2] = c0; C4[nt*2+1] = c1;
    }
  }

  // ---- layer 5: score = elu(C4+b4) . W5[:,t] + b5[t] ----
  int tvals[2][4];
  #pragma unroll
  for (int mtl=0;mtl<2;++mtl)
    #pragma unroll
    for (int r=0;r<4;++r) tvals[mtl][r] = sTy[mtl*16 + quad*4 + r];

  float p[2][4] = {{0.f,0.f,0.f,0.f},{0.f,0.f,0.f,0.f}};
  #pragma unroll
  for (int nt = 0; nt < 8; ++nt){
    int n4 = nt*16 + r16;
    float bv = b4[n4];
    const float* w5r = W5 + n4*LL;
    #pragma unroll
    for (int mtl = 0; mtl < 2; ++mtl){
      f32x4 c = C4[nt*2+mtl];
      #pragma unroll
      for (int r=0;r<4;++r)
        p[mtl][r] += elu_f(c[r] + bv) * w5r[tvals[mtl][r]];
    }
  }
  #pragma unroll
  for (int d = 8; d >= 1; d >>= 1){
    #pragma unroll
    for (int mtl=0;mtl<2;++mtl)
      #pragma unroll
      for (int r=0;r<4;++r)
        p[mtl][r] += __shfl_down(p[mtl][r], d, 16);
  }
  if (r16 == 0){
    #pragma unroll
    for (int mtl=0;mtl<2;++mtl)
      #pragma unroll
      for (int r=0;r<4;++r){
        int m = mtl*16 + quad*4 + r;
        scores[e0 + m] = p[mtl][r] + b5[tvals[mtl][r]];
      }
  }
}

// ---------------------------------------------------------------------------
// Segment softmax / argmax passes (unchanged, verified)
// ---------------------------------------------------------------------------
__global__ void kInitSeg(unsigned* segmax, float* segsum, unsigned* gmax, int* gact){
  int b = blockIdx.x*blockDim.x + threadIdx.x;
  if (b < BB){ segmax[b] = ENC_NEG_INF; segsum[b] = 0.f; gmax[b] = ENC_NEG_INF; gact[b] = 0x7FFFFFFF; }
}

__global__ __launch_bounds__(256) void kSegMax(const float* __restrict__ scores,
                                               const int* __restrict__ eb,
                                               unsigned* __restrict__ segmax){
  __shared__ unsigned l[BB];
  for (int b = threadIdx.x; b < BB; b += 256) l[b] = 0u;
  __syncthreads();
  for (int e = blockIdx.x*256 + threadIdx.x; e < EE; e += gridDim.x*256)
    atomicMax(&l[eb[e]], enc_f(scores[e]));
  __syncthreads();
  for (int b = threadIdx.x; b < BB; b += 256)
    if (l[b]) atomicMax(&segmax[b], l[b]);
}

__global__ __launch_bounds__(256) void kExpSum(const float* __restrict__ scores,
                                               const int* __restrict__ eb,
                                               const unsigned* __restrict__ segmax,
                                               float* __restrict__ segsum,
                                               float* __restrict__ outprobs){
  __shared__ float l[BB];
  for (int b = threadIdx.x; b < BB; b += 256) l[b] = 0.f;
  __syncthreads();
  for (int e = blockIdx.x*256 + threadIdx.x; e < EE; e += gridDim.x*256){
    int b = eb[e];
    float ex = expf(scores[e] - dec_f(segmax[b]));
    outprobs[e] = ex;
    atomicAdd(&l[b], ex);
  }
  __syncthreads();
  for (int b = threadIdx.x; b < BB; b += 256)
    if (l[b] != 0.f) atomicAdd(&segsum[b], l[b]);
}

__global__ __launch_bounds__(256) void kProbMax(float* __restrict__ outprobs,
                                                const int* __restrict__ eb,
                                                const float* __restrict__ segsum,
                                                unsigned* __restrict__ gmax){
  __shared__ unsigned l[BB];
  for (int b = threadIdx.x; b < BB; b += 256) l[b] = 0u;
  __syncthreads();
  for (int e = blockIdx.x*256 + threadIdx.x; e < EE; e += gridDim.x*256){
    int b = eb[e];
    float p = outprobs[e] / segsum[b];
    outprobs[e] = p;
    atomicMax(&l[b], enc_f(p));
  }
  __syncthreads();
  for (int b = threadIdx.x; b < BB; b += 256)
    if (l[b]) atomicMax(&gmax[b], l[b]);
}

__global__ __launch_bounds__(256) void kArgMin(const float* __restrict__ outprobs,
                                               const int* __restrict__ eb,
                                               const unsigned* __restrict__ gmax,
                                               int* __restrict__ gact){
  __shared__ int l[BB];
  for (int b = threadIdx.x; b < BB; b += 256) l[b] = 0x7FFFFFFF;
  __syncthreads();
  for (int e = blockIdx.x*256 + threadIdx.x; e < EE; e += gridDim.x*256){
    int b = eb[e];
    if (enc_f(outprobs[e]) == gmax[b]) atomicMin(&l[b], e);
  }
  __syncthreads();
  for (int b = threadIdx.x; b < BB; b += 256)
    if (l[b] != 0x7FFFFFFF) atomicMin(&gact[b], l[b]);
}

__global__ void kFinal(const unsigned* __restrict__ gmax, const int* __restrict__ gact,
                       float* __restrict__ out){
  int b = threadIdx.x;
  if (b < BB){
    out[EE + b]      = dec_f(gmax[b]);
    out[EE + BB + b] = (float)gact[b];
  }
}

// ---------------------------------------------------------------------------
extern "C" void kernel_launch(void* const* d_in, const int* in_sizes, int n_in,
                              void* d_out, int out_size, void* d_ws, size_t ws_size,
                              hipStream_t stream){
  const float* r0 = (const float*)d_in[0];
  const float* r1 = (const float*)d_in[1];
  const float* W1 = (const float*)d_in[2];
  const float* b1 = (const float*)d_in[3];
  const float* W2 = (const float*)d_in[4];
  const float* b2 = (const float*)d_in[5];
  const float* W3 = (const float*)d_in[6];
  const float* b3 = (const float*)d_in[7];
  const float* W4 = (const float*)d_in[8];
  const float* b4 = (const float*)d_in[9];
  const float* W5 = (const float*)d_in[10];
  const float* b5 = (const float*)d_in[11];
  const int* edge_index = (const int*)d_in[12];
  const int* batch = (const int*)d_in[13];
  const int* y = (const int*)d_in[14];
  float* out = (float*)d_out;

  char* ws = (char*)d_ws;
  size_t off = 0;
  float*    scores = (float*)(ws + off);    off += (size_t)EE*4;
  int*      ebatch = (int*)(ws + off);      off += (size_t)EE*4;
  unsigned* segmax = (unsigned*)(ws + off); off += BB*4;
  float*    segsum = (float*)(ws + off);    off += BB*4;
  unsigned* gmax   = (unsigned*)(ws + off); off += BB*4;
  int*      gact   = (int*)(ws + off);      off += BB*4;
  off = (off + 511) & ~(size_t)511;
  ushort* repsF = (ushort*)(ws + off);      off += (size_t)NN*256*2;   // 51.2 MB
  ushort* W1F   = (ushort*)(ws + off);      off += (size_t)2*8*32*512*2;
  ushort* W2F   = (ushort*)(ws + off);      off += (size_t)2*16*16*512*2;
  ushort* W3F   = (ushort*)(ws + off);      off += (size_t)2*8*8*512*2;
  ushort* W4F   = (ushort*)(ws + off);      off += (size_t)2*4*8*512*2;

  kInitSeg<<<2, 256, 0, stream>>>(segmax, segsum, gmax, gact);
  kReps<<<(NN*16)/256, 256, 0, stream>>>(r0, r1, repsF);
  kPrepW<<<(8*32*64)/256, 256, 0, stream>>>(W1, 512, 8, 32, W1F);
  kPrepW<<<(16*16*64)/256, 256, 0, stream>>>(W2, 256, 16, 16, W2F);
  kPrepW<<<(8*8*64)/256, 256, 0, stream>>>(W3, 128, 8, 8, W3F);
  kPrepW<<<(4*8*64)/256, 256, 0, stream>>>(W4, 128, 4, 8, W4F);

  kMLP<<<EE/32, 64, 0, stream>>>(repsF, W1F, W2F, W3F, W4F,
                                 b1, b2, b3, b4, W5, b5,
                                 edge_index, batch, y, scores, ebatch);

  kSegMax <<<256, 256, 0, stream>>>(scores, ebatch, segmax);
  kExpSum <<<256, 256, 0, stream>>>(scores, ebatch, segmax, segsum, out);
  kProbMax<<<256, 256, 0, stream>>>(out, ebatch, segsum, gmax);
  kArgMin <<<256, 256, 0, stream>>>(out, ebatch, gmax, gact);
  kFinal  <<<1, 512, 0, stream>>>(gmax, gact, out);
}